// Round 1
// baseline (1432.586 us; speedup 1.0000x reference)
//
#include <hip/hip_runtime.h>
#include <float.h>

// Problem constants
#define S_LEN 2048
#define BATCH 32
#define HCH   256
#define DCH   128
#define KCODES 512

__device__ __forceinline__ float lrelu_f(float v) { return v >= 0.f ? v : 0.2f * v; }

// ---------------------------------------------------------------------------
// Weight transpose: W[Cout][Kdim] (Kdim = Cin*3, contiguous (ci,t)) -> WT[Kdim][Cout]
// ---------------------------------------------------------------------------
__global__ void transpose_w_kernel(const float* __restrict__ W, float* __restrict__ WT,
                                   int Cout, int Kdim) {
    int i = blockIdx.x * 256 + threadIdx.x;
    if (i < Kdim * Cout) {
        int k = i / Cout;
        int co = i - k * Cout;
        WT[i] = W[co * Kdim + k];
    }
}

// ---------------------------------------------------------------------------
// Codebook prep: cb[K][D] -> cbT[D][K], cnorm[k] = ||cb[k]||^2
// ---------------------------------------------------------------------------
__global__ void prep_cb_kernel(const float* __restrict__ cb, float* __restrict__ cbT,
                               float* __restrict__ cnorm) {
    int k = blockIdx.x * 256 + threadIdx.x;
    if (k < KCODES) {
        float s = 0.f;
        for (int d = 0; d < DCH; ++d) {
            float v = cb[k * DCH + d];
            s += v * v;
            cbT[d * KCODES + k] = v;
        }
        cnorm[k] = s;
    }
}

// ---------------------------------------------------------------------------
// Encoder conv1: x[B][S] -> h[B][HCH][S], lrelu.  w:[HCH][1][3], bias:[HCH]
// ---------------------------------------------------------------------------
__global__ __launch_bounds__(256) void enc_conv1_kernel(
        const float* __restrict__ x, float* __restrict__ h,
        const float* __restrict__ w, const float* __restrict__ bias) {
    __shared__ float ws[HCH * 3 + HCH];
    int tid = threadIdx.x;
    for (int i = tid; i < HCH * 3 + HCH; i += 256)
        ws[i] = (i < HCH * 3) ? w[i] : bias[i - HCH * 3];
    __syncthreads();
    int b = blockIdx.y;
    int s = blockIdx.x * 256 + tid;
    const float* xb = x + (size_t)b * S_LEN;
    float xm = (s > 0) ? xb[s - 1] : 0.f;
    float x0 = xb[s];
    float xp = (s < S_LEN - 1) ? xb[s + 1] : 0.f;
    float* hb = h + (size_t)b * HCH * S_LEN + s;
    for (int co = 0; co < HCH; ++co) {
        float v = ws[co * 3 + 0] * xm + ws[co * 3 + 1] * x0 + ws[co * 3 + 2] * xp
                + ws[HCH * 3 + co];
        hb[(size_t)co * S_LEN] = lrelu_f(v);
    }
}

// ---------------------------------------------------------------------------
// Generic k=3 SAME conv as implicit GEMM, fp32.
//   in : [B][Cin][S]   out: [B][Cout][S]
//   WT : [Cin*3][Cout] (pre-transposed)   bias:[Cout]
// Block: 256 thr = 16x16, tile 128(co) x 128(s), 8x8 micro-tile per thread.
// Requires Cin % 16 == 0, Cout % 128 == 0 handled via gridDim.y.
// ---------------------------------------------------------------------------
__global__ __launch_bounds__(256) void conv_gemm_kernel(
        const float* __restrict__ in, float* __restrict__ out,
        const float* __restrict__ WT, const float* __restrict__ bias,
        int Cin, int Cout, int do_lrelu) {
    __shared__ float Xs[16][132];   // cols 0..129 used: s = s0 + col - 1
    __shared__ float Ws[48][132];   // [k = ciL*3+t][co]

    int tid = threadIdx.x;
    int tx = tid & 15, ty = tid >> 4;
    int tx4 = tx * 4, ty4 = ty * 4;
    int b = blockIdx.z;
    int s0 = blockIdx.x * 128;
    int co0 = blockIdx.y * 128;

    float acc[8][8];
#pragma unroll
    for (int i = 0; i < 8; ++i)
#pragma unroll
        for (int j = 0; j < 8; ++j) acc[i][j] = 0.f;

    const float* inb = in + (size_t)b * Cin * S_LEN;

    for (int ci0 = 0; ci0 < Cin; ci0 += 16) {
        __syncthreads();
        // X tile: 16 x 130 (halo of 1 each side)
        for (int idx = tid; idx < 16 * 132; idx += 256) {
            int r = idx / 132;
            int c = idx - r * 132;
            float v = 0.f;
            int s = s0 + c - 1;
            if (c < 130 && s >= 0 && s < S_LEN)
                v = inb[(size_t)(ci0 + r) * S_LEN + s];
            Xs[r][c] = v;
        }
        // W tile: 48 x 128, coalesced from WT
        const float* wt = WT + (size_t)(ci0 * 3) * Cout + co0;
        for (int idx = tid; idx < 48 * 128; idx += 256) {
            int r = idx >> 7;
            int c = idx & 127;
            Ws[r][c] = wt[(size_t)r * Cout + c];
        }
        __syncthreads();

#pragma unroll
        for (int dL = 0; dL < 16; ++dL) {
            float x0[6], x1[6];
            {
                float4 a  = *(const float4*)&Xs[dL][tx4];
                float2 b2 = *(const float2*)&Xs[dL][tx4 + 4];
                x0[0] = a.x; x0[1] = a.y; x0[2] = a.z; x0[3] = a.w; x0[4] = b2.x; x0[5] = b2.y;
                float4 c  = *(const float4*)&Xs[dL][64 + tx4];
                float2 d2 = *(const float2*)&Xs[dL][64 + tx4 + 4];
                x1[0] = c.x; x1[1] = c.y; x1[2] = c.z; x1[3] = c.w; x1[4] = d2.x; x1[5] = d2.y;
            }
#pragma unroll
            for (int t = 0; t < 3; ++t) {
                float4 wa = *(const float4*)&Ws[dL * 3 + t][ty4];
                float4 wb = *(const float4*)&Ws[dL * 3 + t][64 + ty4];
                float wr[8] = {wa.x, wa.y, wa.z, wa.w, wb.x, wb.y, wb.z, wb.w};
#pragma unroll
                for (int i = 0; i < 8; ++i) {
#pragma unroll
                    for (int j = 0; j < 4; ++j) {
                        acc[i][j]     = fmaf(wr[i], x0[j + t], acc[i][j]);
                        acc[i][j + 4] = fmaf(wr[i], x1[j + t], acc[i][j + 4]);
                    }
                }
            }
        }
    }

    // epilogue: bias + optional lrelu, float4 stores
#pragma unroll
    for (int i = 0; i < 8; ++i) {
        int co = co0 + ((i < 4) ? (ty4 + i) : (64 + ty4 + i - 4));
        float bv = bias[co];
        float* ob = out + ((size_t)b * Cout + co) * S_LEN + s0;
        float4 v0, v1;
        v0.x = acc[i][0] + bv; v0.y = acc[i][1] + bv; v0.z = acc[i][2] + bv; v0.w = acc[i][3] + bv;
        v1.x = acc[i][4] + bv; v1.y = acc[i][5] + bv; v1.z = acc[i][6] + bv; v1.w = acc[i][7] + bv;
        if (do_lrelu) {
            v0.x = lrelu_f(v0.x); v0.y = lrelu_f(v0.y); v0.z = lrelu_f(v0.z); v0.w = lrelu_f(v0.w);
            v1.x = lrelu_f(v1.x); v1.y = lrelu_f(v1.y); v1.z = lrelu_f(v1.z); v1.w = lrelu_f(v1.w);
        }
        *(float4*)(ob + tx4) = v0;
        *(float4*)(ob + 64 + tx4) = v1;
    }
}

// ---------------------------------------------------------------------------
// VQ argmin: z[B][D][S], cbT[D][K], cnorm[K] -> idx (int + float copies)
// argmin_k (cnorm[k] - 2 * z.c_k); ties -> lowest k (matches jnp.argmin).
// Block: 256 thr = 16x16, n-tile 128 (rows via ty), k-tile 128 (cols via tx).
// ---------------------------------------------------------------------------
__global__ __launch_bounds__(256) void vq_argmin_kernel(
        const float* __restrict__ z, const float* __restrict__ cbT,
        const float* __restrict__ cnorm, int* __restrict__ idx_out,
        float* __restrict__ idx_f_out) {
    __shared__ float Zs[16][132];
    __shared__ float Cs[16][132];
    __shared__ float redv[128][16];
    __shared__ int   redi[128][16];

    int tid = threadIdx.x;
    int tx = tid & 15, ty = tid >> 4;
    int tx4 = tx * 4, ty4 = ty * 4;
    int b = blockIdx.y;
    int s0 = blockIdx.x * 128;

    float best[8];
    int besti[8];
#pragma unroll
    for (int i = 0; i < 8; ++i) { best[i] = FLT_MAX; besti[i] = 0; }

    for (int k0 = 0; k0 < KCODES; k0 += 128) {
        float acc[8][8];
#pragma unroll
        for (int i = 0; i < 8; ++i)
#pragma unroll
            for (int j = 0; j < 8; ++j) acc[i][j] = 0.f;

        for (int d0 = 0; d0 < DCH; d0 += 16) {
            __syncthreads();
            for (int idx = tid; idx < 16 * 128; idx += 256) {
                int r = idx >> 7;
                int c = idx & 127;
                Zs[r][c] = z[((size_t)b * DCH + d0 + r) * S_LEN + s0 + c];
                Cs[r][c] = cbT[(size_t)(d0 + r) * KCODES + k0 + c];
            }
            __syncthreads();
#pragma unroll
            for (int dL = 0; dL < 16; ++dL) {
                float4 za = *(const float4*)&Zs[dL][ty4];
                float4 zb = *(const float4*)&Zs[dL][64 + ty4];
                float4 ca = *(const float4*)&Cs[dL][tx4];
                float4 cb4 = *(const float4*)&Cs[dL][64 + tx4];
                float zz[8] = {za.x, za.y, za.z, za.w, zb.x, zb.y, zb.z, zb.w};
                float cc[8] = {ca.x, ca.y, ca.z, ca.w, cb4.x, cb4.y, cb4.z, cb4.w};
#pragma unroll
                for (int i = 0; i < 8; ++i)
#pragma unroll
                    for (int j = 0; j < 8; ++j)
                        acc[i][j] = fmaf(zz[i], cc[j], acc[i][j]);
            }
        }
        // running argmin update: k ascending within thread
#pragma unroll
        for (int j = 0; j < 8; ++j) {
            int k = k0 + ((j < 4) ? (tx4 + j) : (64 + tx4 + j - 4));
            float cn = cnorm[k];
#pragma unroll
            for (int i = 0; i < 8; ++i) {
                float dv = cn - 2.f * acc[i][j];
                if (dv < best[i]) { best[i] = dv; besti[i] = k; }
            }
        }
    }

    __syncthreads();
#pragma unroll
    for (int i = 0; i < 8; ++i) {
        int n = (i < 4) ? (ty4 + i) : (64 + ty4 + i - 4);
        redv[n][tx] = best[i];
        redi[n][tx] = besti[i];
    }
    __syncthreads();
    if (tid < 128) {
        float bv = redv[tid][0];
        int bi = redi[tid][0];
#pragma unroll
        for (int t2 = 1; t2 < 16; ++t2) {
            float v = redv[tid][t2];
            int ii = redi[tid][t2];
            if (v < bv || (v == bv && ii < bi)) { bv = v; bi = ii; }
        }
        int ng = b * S_LEN + s0 + tid;
        idx_out[ng] = bi;
        idx_f_out[ng] = (float)bi;
    }
}

// ---------------------------------------------------------------------------
// Gather z_q = cb[idx] into [B][D][S] layout + accumulate sum((z - z_q)^2)
// ---------------------------------------------------------------------------
__global__ __launch_bounds__(256) void gather_zq_kernel(
        const float* __restrict__ cb, const int* __restrict__ idxb,
        const float* __restrict__ z, float* __restrict__ zq,
        float* __restrict__ acc_vq) {
    int tid = threadIdx.x;
    int b = blockIdx.y;
    int s = blockIdx.x * 256 + tid;
    int k = idxb[b * S_LEN + s];
    const float* cr = cb + (size_t)k * DCH;
    float sum = 0.f;
    for (int d = 0; d < DCH; ++d) {
        float q = cr[d];
        size_t off = ((size_t)b * DCH + d) * S_LEN + s;
        float zv = z[off];
        zq[off] = q;
        float df = zv - q;
        sum += df * df;
    }
    // block reduction
    for (int off = 32; off > 0; off >>= 1) sum += __shfl_down(sum, off);
    __shared__ float wsum[4];
    if ((tid & 63) == 0) wsum[tid >> 6] = sum;
    __syncthreads();
    if (tid == 0) atomicAdd(acc_vq, wsum[0] + wsum[1] + wsum[2] + wsum[3]);
}

// ---------------------------------------------------------------------------
// Decoder conv3: h[B][HCH][S] -> x_recon[B][S]; + accumulate sum((x - xr)^2)
// w: [1][HCH][3], bias: [1]
// ---------------------------------------------------------------------------
__global__ __launch_bounds__(256) void dec_conv3_kernel(
        const float* __restrict__ h, const float* __restrict__ w,
        const float* __restrict__ bias, const float* __restrict__ x,
        float* __restrict__ xr, float* __restrict__ acc_recon) {
    __shared__ float ws[HCH * 3];
    int tid = threadIdx.x;
    for (int i = tid; i < HCH * 3; i += 256) ws[i] = w[i];
    __syncthreads();
    int b = blockIdx.y;
    int s = blockIdx.x * 256 + tid;
    float acc = bias[0];
    const float* hb = h + (size_t)b * HCH * S_LEN;
    for (int ci = 0; ci < HCH; ++ci) {
        const float* hr = hb + (size_t)ci * S_LEN;
        float hm = (s > 0) ? hr[s - 1] : 0.f;
        float h0 = hr[s];
        float hp = (s < S_LEN - 1) ? hr[s + 1] : 0.f;
        acc = fmaf(ws[ci * 3 + 0], hm, acc);
        acc = fmaf(ws[ci * 3 + 1], h0, acc);
        acc = fmaf(ws[ci * 3 + 2], hp, acc);
    }
    xr[b * S_LEN + s] = acc;
    float df = x[b * S_LEN + s] - acc;
    float sum = df * df;
    for (int off = 32; off > 0; off >>= 1) sum += __shfl_down(sum, off);
    __shared__ float wsum[4];
    if ((tid & 63) == 0) wsum[tid >> 6] = sum;
    __syncthreads();
    if (tid == 0) atomicAdd(acc_recon, wsum[0] + wsum[1] + wsum[2] + wsum[3]);
}

// ---------------------------------------------------------------------------
// Finalize: losses -> d_out tail. accs[0]=vq_sum, accs[1]=recon_sum
// ---------------------------------------------------------------------------
__global__ void finalize_kernel(const float* __restrict__ accs, float* __restrict__ out) {
    if (threadIdx.x == 0) {
        float vqm = accs[0] / ((float)BATCH * S_LEN * DCH);
        float rm  = accs[1] / ((float)BATCH * S_LEN);
        float vq_loss = vqm * 0.05f;
        float commit  = vqm * 0.15f;
        float recon   = rm * 1.0f;
        out[0] = recon + vq_loss + commit;
        out[1] = recon;
        out[2] = vq_loss;
        out[3] = commit;
    }
}

// ---------------------------------------------------------------------------
extern "C" void kernel_launch(void* const* d_in, const int* in_sizes, int n_in,
                              void* d_out, int out_size, void* d_ws, size_t ws_size,
                              hipStream_t stream) {
    const float* x    = (const float*)d_in[0];
    const float* cb   = (const float*)d_in[1];
    const float* ew1  = (const float*)d_in[2];
    const float* eb1  = (const float*)d_in[3];
    const float* ew2  = (const float*)d_in[4];
    const float* eb2  = (const float*)d_in[5];
    const float* ew3  = (const float*)d_in[6];
    const float* eb3  = (const float*)d_in[7];
    const float* dw1  = (const float*)d_in[8];
    const float* db1  = (const float*)d_in[9];
    const float* dw2  = (const float*)d_in[10];
    const float* db2  = (const float*)d_in[11];
    const float* dw3  = (const float*)d_in[12];
    const float* db3  = (const float*)d_in[13];

    float* out = (float*)d_out;
    float* xr    = out;                    // [B*S]
    float* idx_f = out + BATCH * S_LEN;    // [B*S]
    float* loss_out = out + 2 * BATCH * S_LEN; // 4 floats

    // workspace layout (floats)
    float* ws = (float*)d_ws;
    size_t o = 0;
    float* bufA = ws + o; o += (size_t)BATCH * HCH * S_LEN;  // 16.7M floats
    float* bufB = ws + o; o += (size_t)BATCH * HCH * S_LEN;
    float* cbT  = ws + o; o += (size_t)DCH * KCODES;
    float* cnorm = ws + o; o += KCODES;
    float* wt_e2 = ws + o; o += (size_t)HCH * 3 * HCH;   // [768][256]
    float* wt_e3 = ws + o; o += (size_t)HCH * 3 * DCH;   // [768][128]
    float* wt_d1 = ws + o; o += (size_t)DCH * 3 * HCH;   // [384][256]
    float* wt_d2 = ws + o; o += (size_t)HCH * 3 * HCH;   // [768][256]
    int*   idxb  = (int*)(ws + o); o += (size_t)BATCH * S_LEN;
    float* accs  = ws + o; o += 2;   // [0]=vq_sum, [1]=recon_sum

    hipMemsetAsync(accs, 0, 2 * sizeof(float), stream);

    // prep
    prep_cb_kernel<<<2, 256, 0, stream>>>(cb, cbT, cnorm);
    transpose_w_kernel<<<(HCH * 3 * HCH + 255) / 256, 256, 0, stream>>>(ew2, wt_e2, HCH, HCH * 3);
    transpose_w_kernel<<<(HCH * 3 * DCH + 255) / 256, 256, 0, stream>>>(ew3, wt_e3, DCH, HCH * 3);
    transpose_w_kernel<<<(DCH * 3 * HCH + 255) / 256, 256, 0, stream>>>(dw1, wt_d1, HCH, DCH * 3);
    transpose_w_kernel<<<(HCH * 3 * HCH + 255) / 256, 256, 0, stream>>>(dw2, wt_d2, HCH, HCH * 3);

    // encoder
    enc_conv1_kernel<<<dim3(S_LEN / 256, BATCH), 256, 0, stream>>>(x, bufA, ew1, eb1);
    conv_gemm_kernel<<<dim3(S_LEN / 128, HCH / 128, BATCH), 256, 0, stream>>>(
        bufA, bufB, wt_e2, eb2, HCH, HCH, 1);
    conv_gemm_kernel<<<dim3(S_LEN / 128, DCH / 128, BATCH), 256, 0, stream>>>(
        bufB, bufA, wt_e3, eb3, HCH, DCH, 0);   // z -> bufA

    // VQ
    vq_argmin_kernel<<<dim3(S_LEN / 128, BATCH), 256, 0, stream>>>(bufA, cbT, cnorm, idxb, idx_f);
    gather_zq_kernel<<<dim3(S_LEN / 256, BATCH), 256, 0, stream>>>(cb, idxb, bufA, bufB, accs); // z_q -> bufB

    // decoder
    conv_gemm_kernel<<<dim3(S_LEN / 128, HCH / 128, BATCH), 256, 0, stream>>>(
        bufB, bufA, wt_d1, db1, DCH, HCH, 1);
    conv_gemm_kernel<<<dim3(S_LEN / 128, HCH / 128, BATCH), 256, 0, stream>>>(
        bufA, bufB, wt_d2, db2, HCH, HCH, 1);
    dec_conv3_kernel<<<dim3(S_LEN / 256, BATCH), 256, 0, stream>>>(bufB, dw3, db3, x, xr, accs + 1);

    finalize_kernel<<<1, 64, 0, stream>>>(accs, loss_out);
}

// Round 2
// 1120.429 us; speedup vs baseline: 1.2786x; 1.2786x over previous
//
#include <hip/hip_runtime.h>
#include <float.h>

// Problem constants
#define S_LEN 2048
#define BATCH 32
#define HCH   256
#define DCH   128
#define KCODES 512

typedef float  f32x4  __attribute__((ext_vector_type(4)));
typedef short  bf16x8 __attribute__((ext_vector_type(8)));
typedef short  short8 __attribute__((ext_vector_type(8)));

__device__ __forceinline__ float lrelu_f(float v) { return v >= 0.f ? v : 0.2f * v; }

// fp32 -> bf16 bits, round-to-nearest-even (finite values)
__device__ __forceinline__ short f2bf(float f) {
    unsigned u = __float_as_uint(f);
    u = u + 0x7fffu + ((u >> 16) & 1u);
    return (short)(u >> 16);
}
__device__ __forceinline__ float bf2f(unsigned short u) {
    return __uint_as_float(((unsigned)u) << 16);
}

// ---------------------------------------------------------------------------
// Weight transpose: W[Cout][Kdim] -> WT[Kdim][Cout]   (fp32, encoder)
// ---------------------------------------------------------------------------
__global__ void transpose_w_kernel(const float* __restrict__ W, float* __restrict__ WT,
                                   int Cout, int Kdim) {
    int i = blockIdx.x * 256 + threadIdx.x;
    if (i < Kdim * Cout) {
        int k = i / Cout;
        int co = i - k * Cout;
        WT[i] = W[co * Kdim + k];
    }
}

// ---------------------------------------------------------------------------
// Decoder weight prep: dw[Cout=256][Cin][3] fp32 -> wt[3][256][Cin] bf16
// ---------------------------------------------------------------------------
__global__ void prep_wdec_kernel(const float* __restrict__ Wsrc, short* __restrict__ Wdst,
                                 int Cin) {
    int i = blockIdx.x * 256 + threadIdx.x;
    int total = 3 * 256 * Cin;
    if (i < total) {
        int t = i / (256 * Cin);
        int rem = i - t * 256 * Cin;
        int co = rem / Cin;
        int ci = rem - co * Cin;
        Wdst[i] = f2bf(Wsrc[(co * Cin + ci) * 3 + t]);
    }
}

// ---------------------------------------------------------------------------
// Codebook prep: cb[K][D] -> cbT[D][K], cnorm[k] = ||cb[k]||^2
// ---------------------------------------------------------------------------
__global__ void prep_cb_kernel(const float* __restrict__ cb, float* __restrict__ cbT,
                               float* __restrict__ cnorm) {
    int k = blockIdx.x * 256 + threadIdx.x;
    if (k < KCODES) {
        float s = 0.f;
        for (int d = 0; d < DCH; ++d) {
            float v = cb[k * DCH + d];
            s += v * v;
            cbT[d * KCODES + k] = v;
        }
        cnorm[k] = s;
    }
}

// ---------------------------------------------------------------------------
// Encoder conv1: x[B][S] -> h[B][HCH][S], lrelu.
// ---------------------------------------------------------------------------
__global__ __launch_bounds__(256) void enc_conv1_kernel(
        const float* __restrict__ x, float* __restrict__ h,
        const float* __restrict__ w, const float* __restrict__ bias) {
    __shared__ float ws[HCH * 3 + HCH];
    int tid = threadIdx.x;
    for (int i = tid; i < HCH * 3 + HCH; i += 256)
        ws[i] = (i < HCH * 3) ? w[i] : bias[i - HCH * 3];
    __syncthreads();
    int b = blockIdx.y;
    int s = blockIdx.x * 256 + tid;
    const float* xb = x + (size_t)b * S_LEN;
    float xm = (s > 0) ? xb[s - 1] : 0.f;
    float x0 = xb[s];
    float xp = (s < S_LEN - 1) ? xb[s + 1] : 0.f;
    float* hb = h + (size_t)b * HCH * S_LEN + s;
    for (int co = 0; co < HCH; ++co) {
        float v = ws[co * 3 + 0] * xm + ws[co * 3 + 1] * x0 + ws[co * 3 + 2] * xp
                + ws[HCH * 3 + co];
        hb[(size_t)co * S_LEN] = lrelu_f(v);
    }
}

// ---------------------------------------------------------------------------
// Encoder fp32 conv GEMM (unchanged from round 1) — channels-first layout.
// ---------------------------------------------------------------------------
__global__ __launch_bounds__(256) void conv_gemm_kernel(
        const float* __restrict__ in, float* __restrict__ out,
        const float* __restrict__ WT, const float* __restrict__ bias,
        int Cin, int Cout, int do_lrelu) {
    __shared__ float Xs[16][132];
    __shared__ float Ws[48][132];

    int tid = threadIdx.x;
    int tx = tid & 15, ty = tid >> 4;
    int tx4 = tx * 4, ty4 = ty * 4;
    int b = blockIdx.z;
    int s0 = blockIdx.x * 128;
    int co0 = blockIdx.y * 128;

    float acc[8][8];
#pragma unroll
    for (int i = 0; i < 8; ++i)
#pragma unroll
        for (int j = 0; j < 8; ++j) acc[i][j] = 0.f;

    const float* inb = in + (size_t)b * Cin * S_LEN;

    for (int ci0 = 0; ci0 < Cin; ci0 += 16) {
        __syncthreads();
        for (int idx = tid; idx < 16 * 132; idx += 256) {
            int r = idx / 132;
            int c = idx - r * 132;
            float v = 0.f;
            int s = s0 + c - 1;
            if (c < 130 && s >= 0 && s < S_LEN)
                v = inb[(size_t)(ci0 + r) * S_LEN + s];
            Xs[r][c] = v;
        }
        const float* wt = WT + (size_t)(ci0 * 3) * Cout + co0;
        for (int idx = tid; idx < 48 * 128; idx += 256) {
            int r = idx >> 7;
            int c = idx & 127;
            Ws[r][c] = wt[(size_t)r * Cout + c];
        }
        __syncthreads();

#pragma unroll
        for (int dL = 0; dL < 16; ++dL) {
            float x0[6], x1[6];
            {
                float4 a  = *(const float4*)&Xs[dL][tx4];
                float2 b2 = *(const float2*)&Xs[dL][tx4 + 4];
                x0[0] = a.x; x0[1] = a.y; x0[2] = a.z; x0[3] = a.w; x0[4] = b2.x; x0[5] = b2.y;
                float4 c  = *(const float4*)&Xs[dL][64 + tx4];
                float2 d2 = *(const float2*)&Xs[dL][64 + tx4 + 4];
                x1[0] = c.x; x1[1] = c.y; x1[2] = c.z; x1[3] = c.w; x1[4] = d2.x; x1[5] = d2.y;
            }
#pragma unroll
            for (int t = 0; t < 3; ++t) {
                float4 wa = *(const float4*)&Ws[dL * 3 + t][ty4];
                float4 wb = *(const float4*)&Ws[dL * 3 + t][64 + ty4];
                float wr[8] = {wa.x, wa.y, wa.z, wa.w, wb.x, wb.y, wb.z, wb.w};
#pragma unroll
                for (int i = 0; i < 8; ++i) {
#pragma unroll
                    for (int j = 0; j < 4; ++j) {
                        acc[i][j]     = fmaf(wr[i], x0[j + t], acc[i][j]);
                        acc[i][j + 4] = fmaf(wr[i], x1[j + t], acc[i][j + 4]);
                    }
                }
            }
        }
    }

#pragma unroll
    for (int i = 0; i < 8; ++i) {
        int co = co0 + ((i < 4) ? (ty4 + i) : (64 + ty4 + i - 4));
        float bv = bias[co];
        float* ob = out + ((size_t)b * Cout + co) * S_LEN + s0;
        float4 v0, v1;
        v0.x = acc[i][0] + bv; v0.y = acc[i][1] + bv; v0.z = acc[i][2] + bv; v0.w = acc[i][3] + bv;
        v1.x = acc[i][4] + bv; v1.y = acc[i][5] + bv; v1.z = acc[i][6] + bv; v1.w = acc[i][7] + bv;
        if (do_lrelu) {
            v0.x = lrelu_f(v0.x); v0.y = lrelu_f(v0.y); v0.z = lrelu_f(v0.z); v0.w = lrelu_f(v0.w);
            v1.x = lrelu_f(v1.x); v1.y = lrelu_f(v1.y); v1.z = lrelu_f(v1.z); v1.w = lrelu_f(v1.w);
        }
        *(float4*)(ob + tx4) = v0;
        *(float4*)(ob + 64 + tx4) = v1;
    }
}

// ---------------------------------------------------------------------------
// VQ argmin (fp32, unchanged)
// ---------------------------------------------------------------------------
__global__ __launch_bounds__(256) void vq_argmin_kernel(
        const float* __restrict__ z, const float* __restrict__ cbT,
        const float* __restrict__ cnorm, int* __restrict__ idx_out,
        float* __restrict__ idx_f_out) {
    __shared__ float Zs[16][132];
    __shared__ float Cs[16][132];
    __shared__ float redv[128][16];
    __shared__ int   redi[128][16];

    int tid = threadIdx.x;
    int tx = tid & 15, ty = tid >> 4;
    int tx4 = tx * 4, ty4 = ty * 4;
    int b = blockIdx.y;
    int s0 = blockIdx.x * 128;

    float best[8];
    int besti[8];
#pragma unroll
    for (int i = 0; i < 8; ++i) { best[i] = FLT_MAX; besti[i] = 0; }

    for (int k0 = 0; k0 < KCODES; k0 += 128) {
        float acc[8][8];
#pragma unroll
        for (int i = 0; i < 8; ++i)
#pragma unroll
            for (int j = 0; j < 8; ++j) acc[i][j] = 0.f;

        for (int d0 = 0; d0 < DCH; d0 += 16) {
            __syncthreads();
            for (int idx = tid; idx < 16 * 128; idx += 256) {
                int r = idx >> 7;
                int c = idx & 127;
                Zs[r][c] = z[((size_t)b * DCH + d0 + r) * S_LEN + s0 + c];
                Cs[r][c] = cbT[(size_t)(d0 + r) * KCODES + k0 + c];
            }
            __syncthreads();
#pragma unroll
            for (int dL = 0; dL < 16; ++dL) {
                float4 za = *(const float4*)&Zs[dL][ty4];
                float4 zb = *(const float4*)&Zs[dL][64 + ty4];
                float4 ca = *(const float4*)&Cs[dL][tx4];
                float4 cb4 = *(const float4*)&Cs[dL][64 + tx4];
                float zz[8] = {za.x, za.y, za.z, za.w, zb.x, zb.y, zb.z, zb.w};
                float cc[8] = {ca.x, ca.y, ca.z, ca.w, cb4.x, cb4.y, cb4.z, cb4.w};
#pragma unroll
                for (int i = 0; i < 8; ++i)
#pragma unroll
                    for (int j = 0; j < 8; ++j)
                        acc[i][j] = fmaf(zz[i], cc[j], acc[i][j]);
            }
        }
#pragma unroll
        for (int j = 0; j < 8; ++j) {
            int k = k0 + ((j < 4) ? (tx4 + j) : (64 + tx4 + j - 4));
            float cn = cnorm[k];
#pragma unroll
            for (int i = 0; i < 8; ++i) {
                float dv = cn - 2.f * acc[i][j];
                if (dv < best[i]) { best[i] = dv; besti[i] = k; }
            }
        }
    }

    __syncthreads();
#pragma unroll
    for (int i = 0; i < 8; ++i) {
        int n = (i < 4) ? (ty4 + i) : (64 + ty4 + i - 4);
        redv[n][tx] = best[i];
        redi[n][tx] = besti[i];
    }
    __syncthreads();
    if (tid < 128) {
        float bv = redv[tid][0];
        int bi = redi[tid][0];
#pragma unroll
        for (int t2 = 1; t2 < 16; ++t2) {
            float v = redv[tid][t2];
            int ii = redi[tid][t2];
            if (v < bv || (v == bv && ii < bi)) { bv = v; bi = ii; }
        }
        int ng = b * S_LEN + s0 + tid;
        idx_out[ng] = bi;
        idx_f_out[ng] = (float)bi;
    }
}

// ---------------------------------------------------------------------------
// Gather-store: z_q bf16 channels-last [B][S][D].  8 threads per s row.
// ---------------------------------------------------------------------------
__global__ __launch_bounds__(256) void gather_store_kernel(
        const float* __restrict__ cb, const int* __restrict__ idxb,
        short* __restrict__ zq) {
    int tid = threadIdx.x;
    int b = blockIdx.y;
    int s = blockIdx.x * 32 + (tid >> 3);
    int dpart = tid & 7;
    int k = idxb[b * S_LEN + s];
    const float* src = cb + (size_t)k * DCH + dpart * 16;
    float4 f0 = *(const float4*)(src + 0);
    float4 f1 = *(const float4*)(src + 4);
    float4 f2 = *(const float4*)(src + 8);
    float4 f3 = *(const float4*)(src + 12);
    short8 v0 = { f2bf(f0.x), f2bf(f0.y), f2bf(f0.z), f2bf(f0.w),
                  f2bf(f1.x), f2bf(f1.y), f2bf(f1.z), f2bf(f1.w) };
    short8 v1 = { f2bf(f2.x), f2bf(f2.y), f2bf(f2.z), f2bf(f2.w),
                  f2bf(f3.x), f2bf(f3.y), f2bf(f3.z), f2bf(f3.w) };
    short* dst = zq + ((size_t)(b * S_LEN + s)) * DCH + dpart * 16;
    *(short8*)dst = v0;
    *(short8*)(dst + 8) = v1;
}

// ---------------------------------------------------------------------------
// VQ sum: sum((z - cb[idx])^2), fp32 (z in [B][D][S])
// ---------------------------------------------------------------------------
__global__ __launch_bounds__(256) void vqsum_kernel(
        const float* __restrict__ cb, const int* __restrict__ idxb,
        const float* __restrict__ z, float* __restrict__ acc_vq) {
    int tid = threadIdx.x;
    int b = blockIdx.y;
    int s = blockIdx.x * 256 + tid;
    int k = idxb[b * S_LEN + s];
    const float* cr = cb + (size_t)k * DCH;
    float sum = 0.f;
    for (int d = 0; d < DCH; ++d) {
        float q = cr[d];
        float zv = z[((size_t)b * DCH + d) * S_LEN + s];
        float df = zv - q;
        sum += df * df;
    }
    for (int off = 32; off > 0; off >>= 1) sum += __shfl_down(sum, off);
    __shared__ float wsum[4];
    if ((tid & 63) == 0) wsum[tid >> 6] = sum;
    __syncthreads();
    if (tid == 0) atomicAdd(acc_vq, wsum[0] + wsum[1] + wsum[2] + wsum[3]);
}

// ---------------------------------------------------------------------------
// Decoder bf16 MFMA conv (channels-last), k=3 SAME, lrelu fused.
//   in : bf16 [B][S][Cin]     out: bf16 [B][S][256]
//   wt : bf16 [3][256][Cin]   bias: fp32 [256]
// Block 256 thr = 4 waves, tile 128(s) x 128(co); wave = 64x64 via 4x4 MFMAs.
// MFMA 16x16x32: M=s, N=co, K=ci (BK=32 per step, 3 taps via LDS row offset).
// LDS row stride 48 bf16 (96 B) -> balanced banks for b128 fragment reads.
// ---------------------------------------------------------------------------
__global__ __launch_bounds__(256) void conv_mfma_cl(
        const short* __restrict__ in, short* __restrict__ out,
        const short* __restrict__ wt, const float* __restrict__ bias,
        int Cin) {
    __shared__ short smem[24672];        // 49,344 B
    short* Xs = smem;                    // [130][48]
    short* Ws = smem + 130 * 48;         // [3*128][48]

    const int tid = threadIdx.x;
    const int lane = tid & 63;
    const int w = tid >> 6;
    const int m = lane & 15;
    const int q = lane >> 4;
    const int sOff = (w & 1) * 64;
    const int cOff = (w >> 1) * 64;
    const int b = blockIdx.z;
    const int s0 = blockIdx.x * 128;
    const int co0 = blockIdx.y * 128;

    f32x4 acc[4][4];
    f32x4 zero4 = {0.f, 0.f, 0.f, 0.f};
#pragma unroll
    for (int i = 0; i < 4; ++i)
#pragma unroll
        for (int j = 0; j < 4; ++j) acc[i][j] = zero4;

    const short* inb = in + (size_t)b * S_LEN * Cin;

    for (int ci0 = 0; ci0 < Cin; ci0 += 32) {
        __syncthreads();
        // X tile: 130 rows (s0-1 .. s0+128) x 32 ci, 16B chunks
        for (int c = tid; c < 520; c += 256) {
            int r = c >> 2, part = c & 3;
            int s = s0 - 1 + r;
            float4 v = make_float4(0.f, 0.f, 0.f, 0.f);
            if (s >= 0 && s < S_LEN)
                v = *(const float4*)(inb + (size_t)s * Cin + ci0 + part * 8);
            *(float4*)(Xs + r * 48 + part * 8) = v;
        }
        // W tile: [3][128 co][32 ci]
        for (int c = tid; c < 1536; c += 256) {
            int t = c >> 9;
            int rem = c & 511;
            int cr = rem >> 2, part = rem & 3;
            float4 v = *(const float4*)(wt + ((size_t)(t * 256 + co0 + cr)) * Cin + ci0 + part * 8);
            *(float4*)(Ws + (t * 128 + cr) * 48 + part * 8) = v;
        }
        __syncthreads();

#pragma unroll
        for (int t = 0; t < 3; ++t) {
            bf16x8 a[4], bb[4];
#pragma unroll
            for (int i = 0; i < 4; ++i)
                a[i] = *(const bf16x8*)(Xs + (sOff + i * 16 + m + t) * 48 + q * 8);
#pragma unroll
            for (int j = 0; j < 4; ++j)
                bb[j] = *(const bf16x8*)(Ws + (t * 128 + cOff + j * 16 + m) * 48 + q * 8);
#pragma unroll
            for (int i = 0; i < 4; ++i)
#pragma unroll
                for (int j = 0; j < 4; ++j)
                    acc[i][j] = __builtin_amdgcn_mfma_f32_16x16x32_bf16(
                        a[i], bb[j], acc[i][j], 0, 0, 0);
        }
    }

    __syncthreads();   // before overlaying Xs/Ws with epilogue buffer

    // Epilogue: bias + lrelu, repack via LDS, coalesced 16B bf16 stores.
    short* ob = smem + w * (64 * 80);   // per-wave [64][80]
#pragma unroll
    for (int j = 0; j < 4; ++j) {
        float bv = bias[co0 + cOff + j * 16 + m];
#pragma unroll
        for (int i = 0; i < 4; ++i) {
#pragma unroll
            for (int r = 0; r < 4; ++r) {
                float val = acc[i][j][r] + bv;
                val = lrelu_f(val);
                ob[(i * 16 + q * 4 + r) * 80 + j * 16 + m] = f2bf(val);
            }
        }
    }
    // per-wave region: only this wave reads it; compiler inserts lgkm waits
    const int rsel = lane >> 3;
    const int off8 = (lane & 7) * 8;
#pragma unroll
    for (int pass = 0; pass < 8; ++pass) {
        int rr = pass * 8 + rsel;
        short8 v = *(const short8*)(ob + rr * 80 + off8);
        *(short8*)(out + ((size_t)(b * S_LEN + s0 + sOff + rr)) * 256 + co0 + cOff + off8) = v;
    }
}

// ---------------------------------------------------------------------------
// Decoder conv3 (bf16 channels-last input): h[B][S][256] -> xr[B][S], + recon sum
// One wave per s; lane covers 4 ci.
// ---------------------------------------------------------------------------
__global__ __launch_bounds__(256) void dec_conv3_bf16_kernel(
        const short* __restrict__ h, const float* __restrict__ w3,
        const float* __restrict__ b3, const float* __restrict__ x,
        float* __restrict__ xr, float* __restrict__ acc_recon) {
    __shared__ float ws[HCH * 3];
    __shared__ float wsum[4];
    int tid = threadIdx.x;
    for (int i = tid; i < HCH * 3; i += 256) ws[i] = w3[i];
    __syncthreads();
    int wv = tid >> 6, lane = tid & 63;
    int b = blockIdx.y;
    int s = blockIdx.x * 4 + wv;
    int ci0 = lane * 4;
    float acc = 0.f;
    const short* hb = h + (size_t)b * S_LEN * HCH;
#pragma unroll
    for (int t = 0; t < 3; ++t) {
        int sr = s + t - 1;
        if (sr >= 0 && sr < S_LEN) {
            ushort4 u = *(const ushort4*)(hb + (size_t)sr * HCH + ci0);
            acc = fmaf(ws[(ci0 + 0) * 3 + t], bf2f(u.x), acc);
            acc = fmaf(ws[(ci0 + 1) * 3 + t], bf2f(u.y), acc);
            acc = fmaf(ws[(ci0 + 2) * 3 + t], bf2f(u.z), acc);
            acc = fmaf(ws[(ci0 + 3) * 3 + t], bf2f(u.w), acc);
        }
    }
    for (int off = 32; off > 0; off >>= 1) acc += __shfl_down(acc, off);
    if (lane == 0) {
        float tot = acc + b3[0];
        xr[b * S_LEN + s] = tot;
        float df = x[b * S_LEN + s] - tot;
        wsum[wv] = df * df;
    }
    __syncthreads();
    if (tid == 0) atomicAdd(acc_recon, wsum[0] + wsum[1] + wsum[2] + wsum[3]);
}

// ---------------------------------------------------------------------------
__global__ void finalize_kernel(const float* __restrict__ accs, float* __restrict__ out) {
    if (threadIdx.x == 0) {
        float vqm = accs[0] / ((float)BATCH * S_LEN * DCH);
        float rm  = accs[1] / ((float)BATCH * S_LEN);
        float vq_loss = vqm * 0.05f;
        float commit  = vqm * 0.15f;
        float recon   = rm * 1.0f;
        out[0] = recon + vq_loss + commit;
        out[1] = recon;
        out[2] = vq_loss;
        out[3] = commit;
    }
}

// ---------------------------------------------------------------------------
extern "C" void kernel_launch(void* const* d_in, const int* in_sizes, int n_in,
                              void* d_out, int out_size, void* d_ws, size_t ws_size,
                              hipStream_t stream) {
    const float* x    = (const float*)d_in[0];
    const float* cb   = (const float*)d_in[1];
    const float* ew1  = (const float*)d_in[2];
    const float* eb1  = (const float*)d_in[3];
    const float* ew2  = (const float*)d_in[4];
    const float* eb2  = (const float*)d_in[5];
    const float* ew3  = (const float*)d_in[6];
    const float* eb3  = (const float*)d_in[7];
    const float* dw1  = (const float*)d_in[8];
    const float* db1  = (const float*)d_in[9];
    const float* dw2  = (const float*)d_in[10];
    const float* db2  = (const float*)d_in[11];
    const float* dw3  = (const float*)d_in[12];
    const float* db3  = (const float*)d_in[13];

    float* out = (float*)d_out;
    float* xr    = out;
    float* idx_f = out + BATCH * S_LEN;
    float* loss_out = out + 2 * BATCH * S_LEN;

    float* ws = (float*)d_ws;
    size_t o = 0;
    float* bufA = ws + o; o += (size_t)BATCH * HCH * S_LEN;   // 16.7M floats
    float* bufB = ws + o; o += (size_t)BATCH * HCH * S_LEN;
    float* cbT  = ws + o; o += (size_t)DCH * KCODES;
    float* cnorm = ws + o; o += KCODES;
    float* wt_e2 = ws + o; o += (size_t)HCH * 3 * HCH;
    float* wt_e3 = ws + o; o += (size_t)HCH * 3 * DCH;
    short* wbf_d1 = (short*)(ws + o); o += (size_t)(3 * 256 * DCH) / 2;   // bf16
    short* wbf_d2 = (short*)(ws + o); o += (size_t)(3 * 256 * HCH) / 2;   // bf16
    int*   idxb  = (int*)(ws + o); o += (size_t)BATCH * S_LEN;
    float* accs  = ws + o; o += 2;

    // bf16 activation overlays (regions free at time of use)
    short* zq_bf = (short*)bufB;                               // [B][S][D]
    short* h1_bf = zq_bf + (size_t)BATCH * S_LEN * DCH;        // [B][S][H]
    short* h2_bf = (short*)bufA;                               // [B][S][H]

    hipMemsetAsync(accs, 0, 2 * sizeof(float), stream);

    // prep
    prep_cb_kernel<<<2, 256, 0, stream>>>(cb, cbT, cnorm);
    transpose_w_kernel<<<(HCH * 3 * HCH + 255) / 256, 256, 0, stream>>>(ew2, wt_e2, HCH, HCH * 3);
    transpose_w_kernel<<<(HCH * 3 * DCH + 255) / 256, 256, 0, stream>>>(ew3, wt_e3, DCH, HCH * 3);
    prep_wdec_kernel<<<(3 * 256 * DCH + 255) / 256, 256, 0, stream>>>(dw1, wbf_d1, DCH);
    prep_wdec_kernel<<<(3 * 256 * HCH + 255) / 256, 256, 0, stream>>>(dw2, wbf_d2, HCH);

    // encoder (fp32)
    enc_conv1_kernel<<<dim3(S_LEN / 256, BATCH), 256, 0, stream>>>(x, bufA, ew1, eb1);
    conv_gemm_kernel<<<dim3(S_LEN / 128, HCH / 128, BATCH), 256, 0, stream>>>(
        bufA, bufB, wt_e2, eb2, HCH, HCH, 1);
    conv_gemm_kernel<<<dim3(S_LEN / 128, DCH / 128, BATCH), 256, 0, stream>>>(
        bufB, bufA, wt_e3, eb3, HCH, DCH, 0);   // z -> bufA

    // VQ (fp32)
    vq_argmin_kernel<<<dim3(S_LEN / 128, BATCH), 256, 0, stream>>>(bufA, cbT, cnorm, idxb, idx_f);
    gather_store_kernel<<<dim3(S_LEN / 32, BATCH), 256, 0, stream>>>(cb, idxb, zq_bf);
    vqsum_kernel<<<dim3(S_LEN / 256, BATCH), 256, 0, stream>>>(cb, idxb, bufA, accs);

    // decoder (bf16 MFMA, channels-last)
    conv_mfma_cl<<<dim3(S_LEN / 128, 2, BATCH), 256, 0, stream>>>(
        zq_bf, h1_bf, wbf_d1, db1, DCH);
    conv_mfma_cl<<<dim3(S_LEN / 128, 2, BATCH), 256, 0, stream>>>(
        h1_bf, h2_bf, wbf_d2, db2, HCH);
    dec_conv3_bf16_kernel<<<dim3(S_LEN / 4, BATCH), 256, 0, stream>>>(
        h2_bf, dw3, db3, x, xr, accs + 1);

    finalize_kernel<<<1, 64, 0, stream>>>(accs, loss_out);
}

// Round 3
// 901.493 us; speedup vs baseline: 1.5891x; 1.2429x over previous
//
#include <hip/hip_runtime.h>
#include <float.h>

// Problem constants
#define S_LEN 2048
#define BATCH 32
#define HCH   256
#define DCH   128
#define KCODES 512

typedef float  f32x4  __attribute__((ext_vector_type(4)));
typedef short  bf16x8 __attribute__((ext_vector_type(8)));
typedef short  short8 __attribute__((ext_vector_type(8)));

__device__ __forceinline__ float lrelu_f(float v) { return v >= 0.f ? v : 0.2f * v; }

// fp32 -> bf16 bits, round-to-nearest-even (finite values)
__device__ __forceinline__ short f2bf(float f) {
    unsigned u = __float_as_uint(f);
    u = u + 0x7fffu + ((u >> 16) & 1u);
    return (short)(u >> 16);
}
__device__ __forceinline__ float bf2f(unsigned short u) {
    return __uint_as_float(((unsigned)u) << 16);
}

// ---------------------------------------------------------------------------
// Codebook prep: cb[K][D] fp32 -> cb_hi/cb_lo bf16 [K][D], cnorm fp32
// ---------------------------------------------------------------------------
__global__ void prep_cb_split_kernel(const float* __restrict__ cb,
                                     short* __restrict__ cb_hi, short* __restrict__ cb_lo,
                                     float* __restrict__ cnorm) {
    int k = blockIdx.x * 256 + threadIdx.x;
    if (k < KCODES) {
        float s = 0.f;
        for (int d = 0; d < DCH; ++d) {
            float v = cb[k * DCH + d];
            s += v * v;
            short hi = f2bf(v);
            short lo = f2bf(v - bf2f((unsigned short)hi));
            cb_hi[k * DCH + d] = hi;
            cb_lo[k * DCH + d] = lo;
        }
        cnorm[k] = s;
    }
}

// ---------------------------------------------------------------------------
// Encoder weight prep: W[Cout][Cin][3] fp32 -> [3][Cout][Cin] bf16 hi/lo
// ---------------------------------------------------------------------------
__global__ void prep_w_split_kernel(const float* __restrict__ Wsrc,
                                    short* __restrict__ Wh, short* __restrict__ Wl,
                                    int Cout, int Cin) {
    int i = blockIdx.x * 256 + threadIdx.x;
    int total = 3 * Cout * Cin;
    if (i < total) {
        int t = i / (Cout * Cin);
        int rem = i - t * Cout * Cin;
        int co = rem / Cin;
        int ci = rem - co * Cin;
        float v = Wsrc[(co * Cin + ci) * 3 + t];
        short hi = f2bf(v);
        Wh[i] = hi;
        Wl[i] = f2bf(v - bf2f((unsigned short)hi));
    }
}

// ---------------------------------------------------------------------------
// Decoder weight prep: dw[Cout=256][Cin][3] fp32 -> wt[3][256][Cin] bf16
// ---------------------------------------------------------------------------
__global__ void prep_wdec_kernel(const float* __restrict__ Wsrc, short* __restrict__ Wdst,
                                 int Cin) {
    int i = blockIdx.x * 256 + threadIdx.x;
    int total = 3 * 256 * Cin;
    if (i < total) {
        int t = i / (256 * Cin);
        int rem = i - t * 256 * Cin;
        int co = rem / Cin;
        int ci = rem - co * Cin;
        Wdst[i] = f2bf(Wsrc[(co * Cin + ci) * 3 + t]);
    }
}

// ---------------------------------------------------------------------------
// Encoder conv1 channels-last: x[B][S] -> h hi/lo bf16 [B][S][256], lrelu.
// 8 threads per s row (32 co each); coalesced 16B stores.
// ---------------------------------------------------------------------------
__global__ __launch_bounds__(256) void enc_conv1_cl_kernel(
        const float* __restrict__ x, short* __restrict__ h_hi, short* __restrict__ h_lo,
        const float* __restrict__ w, const float* __restrict__ bias) {
    __shared__ float ws[HCH * 3];
    __shared__ float bs[HCH];
    int tid = threadIdx.x;
    for (int i = tid; i < HCH * 3; i += 256) ws[i] = w[i];
    for (int i = tid; i < HCH; i += 256) bs[i] = bias[i];
    __syncthreads();
    int b = blockIdx.y;
    int s = blockIdx.x * 32 + (tid >> 3);
    int cch = tid & 7;
    const float* xb = x + (size_t)b * S_LEN;
    float xm = (s > 0) ? xb[s - 1] : 0.f;
    float x0 = xb[s];
    float xp = (s < S_LEN - 1) ? xb[s + 1] : 0.f;
    size_t base = ((size_t)(b * S_LEN + s)) * HCH + cch * 32;
#pragma unroll
    for (int cc = 0; cc < 4; ++cc) {
        short8 oh, ol;
#pragma unroll
        for (int e = 0; e < 8; ++e) {
            int co = cch * 32 + cc * 8 + e;
            float v = ws[co * 3 + 0] * xm + ws[co * 3 + 1] * x0 + ws[co * 3 + 2] * xp + bs[co];
            v = lrelu_f(v);
            short hi = f2bf(v);
            oh[e] = hi;
            ol[e] = f2bf(v - bf2f((unsigned short)hi));
        }
        *(short8*)(h_hi + base + cc * 8) = oh;
        *(short8*)(h_lo + base + cc * 8) = ol;
    }
}

// ---------------------------------------------------------------------------
// Encoder split-bf16 MFMA conv (channels-last), k=3 SAME.
//   in hi/lo : bf16 [B][S][Cin]   out hi/lo: bf16 [B][S][Cout]
//   wt hi/lo : bf16 [3][Cout][Cin]   bias fp32
// Block 256 = 4 waves; tile 128(s) x 128(co); wave = 64s x 64co.
// X staged in LDS (stride 40 shorts -> 2-way bank alias, free);
// W fragments straight from global (L2-resident).
// 3-term split: hi*wh + hi*wl + lo*wh.
// ---------------------------------------------------------------------------
__global__ __launch_bounds__(256) void conv_mfma_split(
        const short* __restrict__ in_hi, const short* __restrict__ in_lo,
        short* __restrict__ out_hi, short* __restrict__ out_lo,
        const short* __restrict__ wt_hi, const short* __restrict__ wt_lo,
        const float* __restrict__ bias, int Cin, int Cout, int do_lrelu) {
    __shared__ short smem[20800];        // X: 2 x 130 x 40 shorts (41.6 KB)
    short* Xh = smem;
    short* Xl = smem + 130 * 40;

    const int tid = threadIdx.x;
    const int lane = tid & 63;
    const int w = tid >> 6;
    const int m = lane & 15;
    const int q = lane >> 4;
    const int sOff = (w & 1) * 64;
    const int cOff = (w >> 1) * 64;
    const int b = blockIdx.z;
    const int s0 = blockIdx.x * 128;
    const int co0 = blockIdx.y * 128;

    f32x4 acc[4][4];
    f32x4 zero4 = {0.f, 0.f, 0.f, 0.f};
#pragma unroll
    for (int i = 0; i < 4; ++i)
#pragma unroll
        for (int j = 0; j < 4; ++j) acc[i][j] = zero4;

    const short* inhb = in_hi + (size_t)b * S_LEN * Cin;
    const short* inlb = in_lo + (size_t)b * S_LEN * Cin;

    for (int ci0 = 0; ci0 < Cin; ci0 += 32) {
        __syncthreads();
        // X tile: rows s0-1 .. s0+128 (130), 32 ci, hi+lo
        for (int c = tid; c < 520; c += 256) {
            int r = c >> 2, part = c & 3;
            int s = s0 - 1 + r;
            float4 vh = make_float4(0.f, 0.f, 0.f, 0.f);
            float4 vl = vh;
            if (s >= 0 && s < S_LEN) {
                size_t goff = (size_t)s * Cin + ci0 + part * 8;
                vh = *(const float4*)(inhb + goff);
                vl = *(const float4*)(inlb + goff);
            }
            *(float4*)(Xh + r * 40 + part * 8) = vh;
            *(float4*)(Xl + r * 40 + part * 8) = vl;
        }
        __syncthreads();

#pragma unroll
        for (int t = 0; t < 3; ++t) {
            bf16x8 ah[4], al[4], bh[4], bl[4];
#pragma unroll
            for (int i = 0; i < 4; ++i) {
                int row = sOff + i * 16 + m + t;
                ah[i] = *(const bf16x8*)(Xh + row * 40 + q * 8);
                al[i] = *(const bf16x8*)(Xl + row * 40 + q * 8);
            }
#pragma unroll
            for (int j = 0; j < 4; ++j) {
                size_t woff = ((size_t)(t * Cout + co0 + cOff + j * 16 + m)) * Cin + ci0 + q * 8;
                bh[j] = *(const bf16x8*)(wt_hi + woff);
                bl[j] = *(const bf16x8*)(wt_lo + woff);
            }
#pragma unroll
            for (int i = 0; i < 4; ++i)
#pragma unroll
                for (int j = 0; j < 4; ++j) {
                    acc[i][j] = __builtin_amdgcn_mfma_f32_16x16x32_bf16(ah[i], bh[j], acc[i][j], 0, 0, 0);
                    acc[i][j] = __builtin_amdgcn_mfma_f32_16x16x32_bf16(ah[i], bl[j], acc[i][j], 0, 0, 0);
                    acc[i][j] = __builtin_amdgcn_mfma_f32_16x16x32_bf16(al[i], bh[j], acc[i][j], 0, 0, 0);
                }
        }
    }

    // Epilogue: bias (+lrelu), split to hi/lo, repack via LDS, 16B stores.
    // Per-wave region: [64][40] hi + [64][40] lo = 5120 shorts (w*5120).
    short* obH = smem + w * 5120;
    short* obL = obH + 2560;
#pragma unroll
    for (int p = 0; p < 2; ++p) {
        __syncthreads();
#pragma unroll
        for (int jj = 0; jj < 2; ++jj) {
            int j = 2 * p + jj;
            float bv = bias[co0 + cOff + j * 16 + m];
#pragma unroll
            for (int i = 0; i < 4; ++i) {
#pragma unroll
                for (int r = 0; r < 4; ++r) {
                    float val = acc[i][j][r] + bv;
                    if (do_lrelu) val = lrelu_f(val);
                    short hi = f2bf(val);
                    short lo = f2bf(val - bf2f((unsigned short)hi));
                    int row = i * 16 + q * 4 + r;
                    int col = jj * 16 + m;
                    obH[row * 40 + col] = hi;
                    obL[row * 40 + col] = lo;
                }
            }
        }
        __syncthreads();
        // store 64 rows x 32 co for this pass
        const int chunk = lane & 3;
        const int rsub = lane >> 2;
#pragma unroll
        for (int it = 0; it < 4; ++it) {
            int row = it * 16 + rsub;
            short8 vh = *(const short8*)(obH + row * 40 + chunk * 8);
            short8 vl = *(const short8*)(obL + row * 40 + chunk * 8);
            size_t goff = ((size_t)(b * S_LEN + s0 + sOff + row)) * Cout + co0 + cOff + p * 32 + chunk * 8;
            *(short8*)(out_hi + goff) = vh;
            *(short8*)(out_lo + goff) = vl;
        }
    }
}

// ---------------------------------------------------------------------------
// VQ argmin via split-bf16 MFMA.
//   z hi/lo: [N=B*S][128] channels-last; cb hi/lo: [512][128]; cnorm fp32.
// Block 256 = 4 waves; tile 64 n-rows (shared by all waves), z resident in LDS.
// Wave w covers k-slice w*64 within each 256-k chunk (2 chunks).
// d = cnorm[k] - 2*z.c ; running lexicographic argmin, ties -> lowest k.
// ---------------------------------------------------------------------------
__global__ __launch_bounds__(256) void vq_mfma_kernel(
        const short* __restrict__ z_hi, const short* __restrict__ z_lo,
        const short* __restrict__ cb_hi, const short* __restrict__ cb_lo,
        const float* __restrict__ cnorm, int* __restrict__ idx_out,
        float* __restrict__ idx_f_out) {
    __shared__ short smem[2 * 64 * 136];   // Zs hi/lo, stride 136 (34.8 KB)
    __shared__ float redv[64][4];
    __shared__ int   redi[64][4];
    short* Zh = smem;
    short* Zl = smem + 64 * 136;

    const int tid = threadIdx.x;
    const int lane = tid & 63;
    const int w = tid >> 6;
    const int m = lane & 15;
    const int q = lane >> 4;
    const int n0 = blockIdx.x * 64;

    // stage z tile once: 64 rows x 128 d, hi+lo
    for (int c = tid; c < 2048; c += 256) {
        int buf = c >> 10;
        int rem = c & 1023;
        int r = rem >> 4, part = rem & 15;
        size_t goff = (size_t)(n0 + r) * DCH + part * 8;
        float4 v = buf ? *(const float4*)(z_lo + goff) : *(const float4*)(z_hi + goff);
        *(float4*)((buf ? Zl : Zh) + r * 136 + part * 8) = v;
    }
    __syncthreads();

    float best[4][4];
    int besti[4][4];
#pragma unroll
    for (int i = 0; i < 4; ++i)
#pragma unroll
        for (int r = 0; r < 4; ++r) { best[i][r] = FLT_MAX; besti[i][r] = 0; }

    for (int k0 = 0; k0 < KCODES; k0 += 256) {
        f32x4 acc[4][4];
        f32x4 zero4 = {0.f, 0.f, 0.f, 0.f};
#pragma unroll
        for (int i = 0; i < 4; ++i)
#pragma unroll
            for (int j = 0; j < 4; ++j) acc[i][j] = zero4;

#pragma unroll
        for (int d0 = 0; d0 < DCH; d0 += 32) {
            bf16x8 ah[4], al[4], bh[4], bl[4];
#pragma unroll
            for (int i = 0; i < 4; ++i) {
                int row = i * 16 + m;
                ah[i] = *(const bf16x8*)(Zh + row * 136 + d0 + q * 8);
                al[i] = *(const bf16x8*)(Zl + row * 136 + d0 + q * 8);
            }
#pragma unroll
            for (int j = 0; j < 4; ++j) {
                size_t coff = (size_t)(k0 + w * 64 + j * 16 + m) * DCH + d0 + q * 8;
                bh[j] = *(const bf16x8*)(cb_hi + coff);
                bl[j] = *(const bf16x8*)(cb_lo + coff);
            }
#pragma unroll
            for (int i = 0; i < 4; ++i)
#pragma unroll
                for (int j = 0; j < 4; ++j) {
                    acc[i][j] = __builtin_amdgcn_mfma_f32_16x16x32_bf16(ah[i], bh[j], acc[i][j], 0, 0, 0);
                    acc[i][j] = __builtin_amdgcn_mfma_f32_16x16x32_bf16(ah[i], bl[j], acc[i][j], 0, 0, 0);
                    acc[i][j] = __builtin_amdgcn_mfma_f32_16x16x32_bf16(al[i], bh[j], acc[i][j], 0, 0, 0);
                }
        }
        // argmin update (k ascending within lane via j loop)
#pragma unroll
        for (int j = 0; j < 4; ++j) {
            int k = k0 + w * 64 + j * 16 + m;
            float cn = cnorm[k];
#pragma unroll
            for (int i = 0; i < 4; ++i)
#pragma unroll
                for (int r = 0; r < 4; ++r) {
                    float dv = cn - 2.f * acc[i][j][r];
                    if (dv < best[i][r]) { best[i][r] = dv; besti[i][r] = k; }
                }
        }
    }

    // butterfly over m lanes (same q group), lexicographic (v, k) min
#pragma unroll
    for (int mask = 1; mask < 16; mask <<= 1) {
#pragma unroll
        for (int i = 0; i < 4; ++i)
#pragma unroll
            for (int r = 0; r < 4; ++r) {
                float ov = __shfl_xor(best[i][r], mask);
                int oi = __shfl_xor(besti[i][r], mask);
                if (ov < best[i][r] || (ov == best[i][r] && oi < besti[i][r])) {
                    best[i][r] = ov; besti[i][r] = oi;
                }
            }
    }
    if (m == 0) {
#pragma unroll
        for (int i = 0; i < 4; ++i)
#pragma unroll
            for (int r = 0; r < 4; ++r) {
                int srow = i * 16 + q * 4 + r;
                redv[srow][w] = best[i][r];
                redi[srow][w] = besti[i][r];
            }
    }
    __syncthreads();
    if (tid < 64) {
        float bv = redv[tid][0];
        int bi = redi[tid][0];
#pragma unroll
        for (int w2 = 1; w2 < 4; ++w2) {
            float v = redv[tid][w2];
            int ii = redi[tid][w2];
            if (v < bv || (v == bv && ii < bi)) { bv = v; bi = ii; }
        }
        int n = n0 + tid;
        idx_out[n] = bi;
        idx_f_out[n] = (float)bi;
    }
}

// ---------------------------------------------------------------------------
// Gather-store: z_q bf16 channels-last [B][S][D].  8 threads per s row.
// ---------------------------------------------------------------------------
__global__ __launch_bounds__(256) void gather_store_kernel(
        const float* __restrict__ cb, const int* __restrict__ idxb,
        short* __restrict__ zq) {
    int tid = threadIdx.x;
    int b = blockIdx.y;
    int s = blockIdx.x * 32 + (tid >> 3);
    int dpart = tid & 7;
    int k = idxb[b * S_LEN + s];
    const float* src = cb + (size_t)k * DCH + dpart * 16;
    float4 f0 = *(const float4*)(src + 0);
    float4 f1 = *(const float4*)(src + 4);
    float4 f2 = *(const float4*)(src + 8);
    float4 f3 = *(const float4*)(src + 12);
    short8 v0 = { f2bf(f0.x), f2bf(f0.y), f2bf(f0.z), f2bf(f0.w),
                  f2bf(f1.x), f2bf(f1.y), f2bf(f1.z), f2bf(f1.w) };
    short8 v1 = { f2bf(f2.x), f2bf(f2.y), f2bf(f2.z), f2bf(f2.w),
                  f2bf(f3.x), f2bf(f3.y), f2bf(f3.z), f2bf(f3.w) };
    short* dst = zq + ((size_t)(b * S_LEN + s)) * DCH + dpart * 16;
    *(short8*)dst = v0;
    *(short8*)(dst + 8) = v1;
}

// ---------------------------------------------------------------------------
// VQ sum: sum((z - cb[idx])^2); z from hi/lo channels-last. One wave per row.
// ---------------------------------------------------------------------------
__global__ __launch_bounds__(256) void vqsum_cl_kernel(
        const short* __restrict__ z_hi, const short* __restrict__ z_lo,
        const float* __restrict__ cb, const int* __restrict__ idxb,
        float* __restrict__ acc_vq) {
    __shared__ float wsum[4];
    int tid = threadIdx.x;
    int wv = tid >> 6, lane = tid & 63;
    int n = blockIdx.x * 4 + wv;
    int k = idxb[n];
    ushort2 uh = *(const ushort2*)(z_hi + (size_t)n * DCH + lane * 2);
    ushort2 ul = *(const ushort2*)(z_lo + (size_t)n * DCH + lane * 2);
    float2 c2 = *(const float2*)(cb + (size_t)k * DCH + lane * 2);
    float z0 = bf2f(uh.x) + bf2f(ul.x);
    float z1 = bf2f(uh.y) + bf2f(ul.y);
    float d0 = z0 - c2.x, d1 = z1 - c2.y;
    float sum = d0 * d0 + d1 * d1;
    for (int off = 32; off > 0; off >>= 1) sum += __shfl_down(sum, off);
    if (lane == 0) wsum[wv] = sum;
    __syncthreads();
    if (tid == 0) atomicAdd(acc_vq, wsum[0] + wsum[1] + wsum[2] + wsum[3]);
}

// ---------------------------------------------------------------------------
// Decoder bf16 MFMA conv (channels-last), unchanged from round 2.
// ---------------------------------------------------------------------------
__global__ __launch_bounds__(256) void conv_mfma_cl(
        const short* __restrict__ in, short* __restrict__ out,
        const short* __restrict__ wt, const float* __restrict__ bias,
        int Cin) {
    __shared__ short smem[24672];
    short* Xs = smem;
    short* Ws = smem + 130 * 48;

    const int tid = threadIdx.x;
    const int lane = tid & 63;
    const int w = tid >> 6;
    const int m = lane & 15;
    const int q = lane >> 4;
    const int sOff = (w & 1) * 64;
    const int cOff = (w >> 1) * 64;
    const int b = blockIdx.z;
    const int s0 = blockIdx.x * 128;
    const int co0 = blockIdx.y * 128;

    f32x4 acc[4][4];
    f32x4 zero4 = {0.f, 0.f, 0.f, 0.f};
#pragma unroll
    for (int i = 0; i < 4; ++i)
#pragma unroll
        for (int j = 0; j < 4; ++j) acc[i][j] = zero4;

    const short* inb = in + (size_t)b * S_LEN * Cin;

    for (int ci0 = 0; ci0 < Cin; ci0 += 32) {
        __syncthreads();
        for (int c = tid; c < 520; c += 256) {
            int r = c >> 2, part = c & 3;
            int s = s0 - 1 + r;
            float4 v = make_float4(0.f, 0.f, 0.f, 0.f);
            if (s >= 0 && s < S_LEN)
                v = *(const float4*)(inb + (size_t)s * Cin + ci0 + part * 8);
            *(float4*)(Xs + r * 48 + part * 8) = v;
        }
        for (int c = tid; c < 1536; c += 256) {
            int t = c >> 9;
            int rem = c & 511;
            int cr = rem >> 2, part = rem & 3;
            float4 v = *(const float4*)(wt + ((size_t)(t * 256 + co0 + cr)) * Cin + ci0 + part * 8);
            *(float4*)(Ws + (t * 128 + cr) * 48 + part * 8) = v;
        }
        __syncthreads();

#pragma unroll
        for (int t = 0; t < 3; ++t) {
            bf16x8 a[4], bb[4];
#pragma unroll
            for (int i = 0; i < 4; ++i)
                a[i] = *(const bf16x8*)(Xs + (sOff + i * 16 + m + t) * 48 + q * 8);
#pragma unroll
            for (int j = 0; j < 4; ++j)
                bb[j] = *(const bf16x8*)(Ws + (t * 128 + cOff + j * 16 + m) * 48 + q * 8);
#pragma unroll
            for (int i = 0; i < 4; ++i)
#pragma unroll
                for (int j = 0; j < 4; ++j)
                    acc[i][j] = __builtin_amdgcn_mfma_f32_16x16x32_bf16(
                        a[i], bb[j], acc[i][j], 0, 0, 0);
        }
    }

    __syncthreads();

    short* ob = smem + w * (64 * 80);
#pragma unroll
    for (int j = 0; j < 4; ++j) {
        float bv = bias[co0 + cOff + j * 16 + m];
#pragma unroll
        for (int i = 0; i < 4; ++i) {
#pragma unroll
            for (int r = 0; r < 4; ++r) {
                float val = acc[i][j][r] + bv;
                val = lrelu_f(val);
                ob[(i * 16 + q * 4 + r) * 80 + j * 16 + m] = f2bf(val);
            }
        }
    }
    const int rsel = lane >> 3;
    const int off8 = (lane & 7) * 8;
#pragma unroll
    for (int pass = 0; pass < 8; ++pass) {
        int rr = pass * 8 + rsel;
        short8 v = *(const short8*)(ob + rr * 80 + off8);
        *(short8*)(out + ((size_t)(b * S_LEN + s0 + sOff + rr)) * 256 + co0 + cOff + off8) = v;
    }
}

// ---------------------------------------------------------------------------
// Decoder conv3 (bf16 channels-last input): h[B][S][256] -> xr[B][S], + recon sum
// ---------------------------------------------------------------------------
__global__ __launch_bounds__(256) void dec_conv3_bf16_kernel(
        const short* __restrict__ h, const float* __restrict__ w3,
        const float* __restrict__ b3, const float* __restrict__ x,
        float* __restrict__ xr, float* __restrict__ acc_recon) {
    __shared__ float ws[HCH * 3];
    __shared__ float wsum[4];
    int tid = threadIdx.x;
    for (int i = tid; i < HCH * 3; i += 256) ws[i] = w3[i];
    __syncthreads();
    int wv = tid >> 6, lane = tid & 63;
    int b = blockIdx.y;
    int s = blockIdx.x * 4 + wv;
    int ci0 = lane * 4;
    float acc = 0.f;
    const short* hb = h + (size_t)b * S_LEN * HCH;
#pragma unroll
    for (int t = 0; t < 3; ++t) {
        int sr = s + t - 1;
        if (sr >= 0 && sr < S_LEN) {
            ushort4 u = *(const ushort4*)(hb + (size_t)sr * HCH + ci0);
            acc = fmaf(ws[(ci0 + 0) * 3 + t], bf2f(u.x), acc);
            acc = fmaf(ws[(ci0 + 1) * 3 + t], bf2f(u.y), acc);
            acc = fmaf(ws[(ci0 + 2) * 3 + t], bf2f(u.z), acc);
            acc = fmaf(ws[(ci0 + 3) * 3 + t], bf2f(u.w), acc);
        }
    }
    for (int off = 32; off > 0; off >>= 1) acc += __shfl_down(acc, off);
    if (lane == 0) {
        float tot = acc + b3[0];
        xr[b * S_LEN + s] = tot;
        float df = x[b * S_LEN + s] - tot;
        wsum[wv] = df * df;
    }
    __syncthreads();
    if (tid == 0) atomicAdd(acc_recon, wsum[0] + wsum[1] + wsum[2] + wsum[3]);
}

// ---------------------------------------------------------------------------
__global__ void finalize_kernel(const float* __restrict__ accs, float* __restrict__ out) {
    if (threadIdx.x == 0) {
        float vqm = accs[0] / ((float)BATCH * S_LEN * DCH);
        float rm  = accs[1] / ((float)BATCH * S_LEN);
        float vq_loss = vqm * 0.05f;
        float commit  = vqm * 0.15f;
        float recon   = rm * 1.0f;
        out[0] = recon + vq_loss + commit;
        out[1] = recon;
        out[2] = vq_loss;
        out[3] = commit;
    }
}

// ---------------------------------------------------------------------------
extern "C" void kernel_launch(void* const* d_in, const int* in_sizes, int n_in,
                              void* d_out, int out_size, void* d_ws, size_t ws_size,
                              hipStream_t stream) {
    const float* x    = (const float*)d_in[0];
    const float* cb   = (const float*)d_in[1];
    const float* ew1  = (const float*)d_in[2];
    const float* eb1  = (const float*)d_in[3];
    const float* ew2  = (const float*)d_in[4];
    const float* eb2  = (const float*)d_in[5];
    const float* ew3  = (const float*)d_in[6];
    const float* eb3  = (const float*)d_in[7];
    const float* dw1  = (const float*)d_in[8];
    const float* db1  = (const float*)d_in[9];
    const float* dw2  = (const float*)d_in[10];
    const float* db2  = (const float*)d_in[11];
    const float* dw3  = (const float*)d_in[12];
    const float* db3  = (const float*)d_in[13];

    float* out = (float*)d_out;
    float* xr    = out;
    float* idx_f = out + BATCH * S_LEN;
    float* loss_out = out + 2 * BATCH * S_LEN;

    const size_t NH = (size_t)BATCH * S_LEN * HCH;   // 16,777,216
    const size_t ND = (size_t)BATCH * S_LEN * DCH;   // 8,388,608

    short* sp = (short*)d_ws;
    // arena A [0, 2*NH): h1 hi/lo -> later z hi/lo -> later h1d
    short* h1_hi = sp;
    short* h1_lo = sp + NH;
    short* z_hi  = sp;            // overlays h1 (dead after conv2)
    short* z_lo  = sp + ND;
    short* h1d_bf = sp;           // overlays z (dead after vq+vqsum+gather)
    // arena B [2*NH, 4*NH): h2 hi/lo -> later zq + h2d
    short* h2_hi = sp + 2 * NH;
    short* h2_lo = sp + 3 * NH;
    short* zq_bf = sp + 2 * NH;   // overlays h2 (dead after conv3)
    short* h2d_bf = sp + 3 * NH;  // distinct from zq region
    // small buffers
    short* sm = sp + 4 * NH;
    short* cb_hi = sm; sm += KCODES * DCH;
    short* cb_lo = sm; sm += KCODES * DCH;
    short* w2_hi = sm; sm += 3 * HCH * HCH;
    short* w2_lo = sm; sm += 3 * HCH * HCH;
    short* w3_hi = sm; sm += 3 * DCH * HCH;
    short* w3_lo = sm; sm += 3 * DCH * HCH;
    short* wbf_d1 = sm; sm += 3 * 256 * DCH;
    short* wbf_d2 = sm; sm += 3 * 256 * HCH;
    float* cnorm = (float*)sm;
    int* idxb = (int*)(cnorm + KCODES);
    float* accs = (float*)(idxb + BATCH * S_LEN);

    hipMemsetAsync(accs, 0, 2 * sizeof(float), stream);

    // prep
    prep_cb_split_kernel<<<2, 256, 0, stream>>>(cb, cb_hi, cb_lo, cnorm);
    prep_w_split_kernel<<<(3 * HCH * HCH + 255) / 256, 256, 0, stream>>>(ew2, w2_hi, w2_lo, HCH, HCH);
    prep_w_split_kernel<<<(3 * DCH * HCH + 255) / 256, 256, 0, stream>>>(ew3, w3_hi, w3_lo, DCH, HCH);
    prep_wdec_kernel<<<(3 * 256 * DCH + 255) / 256, 256, 0, stream>>>(dw1, wbf_d1, DCH);
    prep_wdec_kernel<<<(3 * 256 * HCH + 255) / 256, 256, 0, stream>>>(dw2, wbf_d2, HCH);

    // encoder (split-bf16 MFMA)
    enc_conv1_cl_kernel<<<dim3(S_LEN / 32, BATCH), 256, 0, stream>>>(x, h1_hi, h1_lo, ew1, eb1);
    conv_mfma_split<<<dim3(S_LEN / 128, HCH / 128, BATCH), 256, 0, stream>>>(
        h1_hi, h1_lo, h2_hi, h2_lo, w2_hi, w2_lo, eb2, HCH, HCH, 1);
    conv_mfma_split<<<dim3(S_LEN / 128, DCH / 128, BATCH), 256, 0, stream>>>(
        h2_hi, h2_lo, z_hi, z_lo, w3_hi, w3_lo, eb3, HCH, DCH, 0);

    // VQ
    vq_mfma_kernel<<<(BATCH * S_LEN) / 64, 256, 0, stream>>>(
        z_hi, z_lo, cb_hi, cb_lo, cnorm, idxb, idx_f);
    gather_store_kernel<<<dim3(S_LEN / 32, BATCH), 256, 0, stream>>>(cb, idxb, zq_bf);
    vqsum_cl_kernel<<<(BATCH * S_LEN) / 4, 256, 0, stream>>>(z_hi, z_lo, cb, idxb, accs);

    // decoder (bf16 MFMA)
    conv_mfma_cl<<<dim3(S_LEN / 128, 2, BATCH), 256, 0, stream>>>(
        zq_bf, h1d_bf, wbf_d1, db1, DCH);
    conv_mfma_cl<<<dim3(S_LEN / 128, 2, BATCH), 256, 0, stream>>>(
        h1d_bf, h2d_bf, wbf_d2, db2, HCH);
    dec_conv3_bf16_kernel<<<dim3(S_LEN / 4, BATCH), 256, 0, stream>>>(
        h2d_bf, dw3, db3, x, xr, accs + 1);

    finalize_kernel<<<1, 64, 0, stream>>>(accs, loss_out);
}

// Round 4
// 524.670 us; speedup vs baseline: 2.7305x; 1.7182x over previous
//
#include <hip/hip_runtime.h>
#include <float.h>

// Problem constants
#define S_LEN 2048
#define BATCH 32
#define HCH   256
#define DCH   128
#define KCODES 512

typedef float  f32x4  __attribute__((ext_vector_type(4)));
typedef short  bf16x8 __attribute__((ext_vector_type(8)));
typedef short  short8 __attribute__((ext_vector_type(8)));

__device__ __forceinline__ float lrelu_f(float v) { return v >= 0.f ? v : 0.2f * v; }

// fp32 -> bf16 bits, round-to-nearest-even (finite values)
__device__ __forceinline__ short f2bf(float f) {
    unsigned u = __float_as_uint(f);
    u = u + 0x7fffu + ((u >> 16) & 1u);
    return (short)(u >> 16);
}
__device__ __forceinline__ float bf2f(unsigned short u) {
    return __uint_as_float(((unsigned)u) << 16);
}

// ---------------------------------------------------------------------------
// Codebook prep: cb[K][D] fp32 -> cb_hi/cb_lo bf16 [K][D], cnorm fp32
// ---------------------------------------------------------------------------
__global__ void prep_cb_split_kernel(const float* __restrict__ cb,
                                     short* __restrict__ cb_hi, short* __restrict__ cb_lo,
                                     float* __restrict__ cnorm) {
    int k = blockIdx.x * 256 + threadIdx.x;
    if (k < KCODES) {
        float s = 0.f;
        for (int d = 0; d < DCH; ++d) {
            float v = cb[k * DCH + d];
            s += v * v;
            short hi = f2bf(v);
            short lo = f2bf(v - bf2f((unsigned short)hi));
            cb_hi[k * DCH + d] = hi;
            cb_lo[k * DCH + d] = lo;
        }
        cnorm[k] = s;
    }
}

// ---------------------------------------------------------------------------
// Encoder weight prep: W[Cout][Cin][3] fp32 -> [3][Cout][Cin] bf16 hi/lo
// ---------------------------------------------------------------------------
__global__ void prep_w_split_kernel(const float* __restrict__ Wsrc,
                                    short* __restrict__ Wh, short* __restrict__ Wl,
                                    int Cout, int Cin) {
    int i = blockIdx.x * 256 + threadIdx.x;
    int total = 3 * Cout * Cin;
    if (i < total) {
        int t = i / (Cout * Cin);
        int rem = i - t * Cout * Cin;
        int co = rem / Cin;
        int ci = rem - co * Cin;
        float v = Wsrc[(co * Cin + ci) * 3 + t];
        short hi = f2bf(v);
        Wh[i] = hi;
        Wl[i] = f2bf(v - bf2f((unsigned short)hi));
    }
}

// ---------------------------------------------------------------------------
// Decoder weight prep: dw[Cout=256][Cin][3] fp32 -> wt[3][256][Cin] bf16
// ---------------------------------------------------------------------------
__global__ void prep_wdec_kernel(const float* __restrict__ Wsrc, short* __restrict__ Wdst,
                                 int Cin) {
    int i = blockIdx.x * 256 + threadIdx.x;
    int total = 3 * 256 * Cin;
    if (i < total) {
        int t = i / (256 * Cin);
        int rem = i - t * 256 * Cin;
        int co = rem / Cin;
        int ci = rem - co * Cin;
        Wdst[i] = f2bf(Wsrc[(co * Cin + ci) * 3 + t]);
    }
}

// ---------------------------------------------------------------------------
// Decoder conv3 weight repack: dw3[ci*3+t] fp32 -> w3t[t*256+ci] fp32
// ---------------------------------------------------------------------------
__global__ void prep_w3t_kernel(const float* __restrict__ w3, float* __restrict__ w3t) {
    int i = blockIdx.x * 256 + threadIdx.x;
    if (i < 768) {
        int t = i / 256, ci = i - t * 256;
        w3t[i] = w3[ci * 3 + t];
    }
}

// ---------------------------------------------------------------------------
// Encoder conv1 channels-last: x[B][S] -> h hi/lo bf16 [B][S][256], lrelu.
// ---------------------------------------------------------------------------
__global__ __launch_bounds__(256) void enc_conv1_cl_kernel(
        const float* __restrict__ x, short* __restrict__ h_hi, short* __restrict__ h_lo,
        const float* __restrict__ w, const float* __restrict__ bias) {
    __shared__ float ws[HCH * 3];
    __shared__ float bs[HCH];
    int tid = threadIdx.x;
    for (int i = tid; i < HCH * 3; i += 256) ws[i] = w[i];
    for (int i = tid; i < HCH; i += 256) bs[i] = bias[i];
    __syncthreads();
    int b = blockIdx.y;
    int s = blockIdx.x * 32 + (tid >> 3);
    int cch = tid & 7;
    const float* xb = x + (size_t)b * S_LEN;
    float xm = (s > 0) ? xb[s - 1] : 0.f;
    float x0 = xb[s];
    float xp = (s < S_LEN - 1) ? xb[s + 1] : 0.f;
    size_t base = ((size_t)(b * S_LEN + s)) * HCH + cch * 32;
#pragma unroll
    for (int cc = 0; cc < 4; ++cc) {
        short8 oh, ol;
#pragma unroll
        for (int e = 0; e < 8; ++e) {
            int co = cch * 32 + cc * 8 + e;
            float v = ws[co * 3 + 0] * xm + ws[co * 3 + 1] * x0 + ws[co * 3 + 2] * xp + bs[co];
            v = lrelu_f(v);
            short hi = f2bf(v);
            oh[e] = hi;
            ol[e] = f2bf(v - bf2f((unsigned short)hi));
        }
        *(short8*)(h_hi + base + cc * 8) = oh;
        *(short8*)(h_lo + base + cc * 8) = ol;
    }
}

// ---------------------------------------------------------------------------
// Encoder split-bf16 MFMA conv (channels-last), k=3 SAME.  (unchanged)
// ---------------------------------------------------------------------------
__global__ __launch_bounds__(256) void conv_mfma_split(
        const short* __restrict__ in_hi, const short* __restrict__ in_lo,
        short* __restrict__ out_hi, short* __restrict__ out_lo,
        const short* __restrict__ wt_hi, const short* __restrict__ wt_lo,
        const float* __restrict__ bias, int Cin, int Cout, int do_lrelu) {
    __shared__ short smem[20800];        // X: 2 x 130 x 40 shorts (41.6 KB)
    short* Xh = smem;
    short* Xl = smem + 130 * 40;

    const int tid = threadIdx.x;
    const int lane = tid & 63;
    const int w = tid >> 6;
    const int m = lane & 15;
    const int q = lane >> 4;
    const int sOff = (w & 1) * 64;
    const int cOff = (w >> 1) * 64;
    const int b = blockIdx.z;
    const int s0 = blockIdx.x * 128;
    const int co0 = blockIdx.y * 128;

    f32x4 acc[4][4];
    f32x4 zero4 = {0.f, 0.f, 0.f, 0.f};
#pragma unroll
    for (int i = 0; i < 4; ++i)
#pragma unroll
        for (int j = 0; j < 4; ++j) acc[i][j] = zero4;

    const short* inhb = in_hi + (size_t)b * S_LEN * Cin;
    const short* inlb = in_lo + (size_t)b * S_LEN * Cin;

    for (int ci0 = 0; ci0 < Cin; ci0 += 32) {
        __syncthreads();
        for (int c = tid; c < 520; c += 256) {
            int r = c >> 2, part = c & 3;
            int s = s0 - 1 + r;
            float4 vh = make_float4(0.f, 0.f, 0.f, 0.f);
            float4 vl = vh;
            if (s >= 0 && s < S_LEN) {
                size_t goff = (size_t)s * Cin + ci0 + part * 8;
                vh = *(const float4*)(inhb + goff);
                vl = *(const float4*)(inlb + goff);
            }
            *(float4*)(Xh + r * 40 + part * 8) = vh;
            *(float4*)(Xl + r * 40 + part * 8) = vl;
        }
        __syncthreads();

#pragma unroll
        for (int t = 0; t < 3; ++t) {
            bf16x8 ah[4], al[4], bh[4], bl[4];
#pragma unroll
            for (int i = 0; i < 4; ++i) {
                int row = sOff + i * 16 + m + t;
                ah[i] = *(const bf16x8*)(Xh + row * 40 + q * 8);
                al[i] = *(const bf16x8*)(Xl + row * 40 + q * 8);
            }
#pragma unroll
            for (int j = 0; j < 4; ++j) {
                size_t woff = ((size_t)(t * Cout + co0 + cOff + j * 16 + m)) * Cin + ci0 + q * 8;
                bh[j] = *(const bf16x8*)(wt_hi + woff);
                bl[j] = *(const bf16x8*)(wt_lo + woff);
            }
#pragma unroll
            for (int i = 0; i < 4; ++i)
#pragma unroll
                for (int j = 0; j < 4; ++j) {
                    acc[i][j] = __builtin_amdgcn_mfma_f32_16x16x32_bf16(ah[i], bh[j], acc[i][j], 0, 0, 0);
                    acc[i][j] = __builtin_amdgcn_mfma_f32_16x16x32_bf16(ah[i], bl[j], acc[i][j], 0, 0, 0);
                    acc[i][j] = __builtin_amdgcn_mfma_f32_16x16x32_bf16(al[i], bh[j], acc[i][j], 0, 0, 0);
                }
        }
    }

    short* obH = smem + w * 5120;
    short* obL = obH + 2560;
#pragma unroll
    for (int p = 0; p < 2; ++p) {
        __syncthreads();
#pragma unroll
        for (int jj = 0; jj < 2; ++jj) {
            int j = 2 * p + jj;
            float bv = bias[co0 + cOff + j * 16 + m];
#pragma unroll
            for (int i = 0; i < 4; ++i) {
#pragma unroll
                for (int r = 0; r < 4; ++r) {
                    float val = acc[i][j][r] + bv;
                    if (do_lrelu) val = lrelu_f(val);
                    short hi = f2bf(val);
                    short lo = f2bf(val - bf2f((unsigned short)hi));
                    int row = i * 16 + q * 4 + r;
                    int col = jj * 16 + m;
                    obH[row * 40 + col] = hi;
                    obL[row * 40 + col] = lo;
                }
            }
        }
        __syncthreads();
        const int chunk = lane & 3;
        const int rsub = lane >> 2;
#pragma unroll
        for (int it = 0; it < 4; ++it) {
            int row = it * 16 + rsub;
            short8 vh = *(const short8*)(obH + row * 40 + chunk * 8);
            short8 vl = *(const short8*)(obL + row * 40 + chunk * 8);
            size_t goff = ((size_t)(b * S_LEN + s0 + sOff + row)) * Cout + co0 + cOff + p * 32 + chunk * 8;
            *(short8*)(out_hi + goff) = vh;
            *(short8*)(out_lo + goff) = vl;
        }
    }
}

// ---------------------------------------------------------------------------
// VQ argmin via split-bf16 MFMA.  (unchanged)
// ---------------------------------------------------------------------------
__global__ __launch_bounds__(256) void vq_mfma_kernel(
        const short* __restrict__ z_hi, const short* __restrict__ z_lo,
        const short* __restrict__ cb_hi, const short* __restrict__ cb_lo,
        const float* __restrict__ cnorm, int* __restrict__ idx_out,
        float* __restrict__ idx_f_out) {
    __shared__ short smem[2 * 64 * 136];
    __shared__ float redv[64][4];
    __shared__ int   redi[64][4];
    short* Zh = smem;
    short* Zl = smem + 64 * 136;

    const int tid = threadIdx.x;
    const int lane = tid & 63;
    const int w = tid >> 6;
    const int m = lane & 15;
    const int q = lane >> 4;
    const int n0 = blockIdx.x * 64;

    for (int c = tid; c < 2048; c += 256) {
        int buf = c >> 10;
        int rem = c & 1023;
        int r = rem >> 4, part = rem & 15;
        size_t goff = (size_t)(n0 + r) * DCH + part * 8;
        float4 v = buf ? *(const float4*)(z_lo + goff) : *(const float4*)(z_hi + goff);
        *(float4*)((buf ? Zl : Zh) + r * 136 + part * 8) = v;
    }
    __syncthreads();

    float best[4][4];
    int besti[4][4];
#pragma unroll
    for (int i = 0; i < 4; ++i)
#pragma unroll
        for (int r = 0; r < 4; ++r) { best[i][r] = FLT_MAX; besti[i][r] = 0; }

    for (int k0 = 0; k0 < KCODES; k0 += 256) {
        f32x4 acc[4][4];
        f32x4 zero4 = {0.f, 0.f, 0.f, 0.f};
#pragma unroll
        for (int i = 0; i < 4; ++i)
#pragma unroll
            for (int j = 0; j < 4; ++j) acc[i][j] = zero4;

#pragma unroll
        for (int d0 = 0; d0 < DCH; d0 += 32) {
            bf16x8 ah[4], al[4], bh[4], bl[4];
#pragma unroll
            for (int i = 0; i < 4; ++i) {
                int row = i * 16 + m;
                ah[i] = *(const bf16x8*)(Zh + row * 136 + d0 + q * 8);
                al[i] = *(const bf16x8*)(Zl + row * 136 + d0 + q * 8);
            }
#pragma unroll
            for (int j = 0; j < 4; ++j) {
                size_t coff = (size_t)(k0 + w * 64 + j * 16 + m) * DCH + d0 + q * 8;
                bh[j] = *(const bf16x8*)(cb_hi + coff);
                bl[j] = *(const bf16x8*)(cb_lo + coff);
            }
#pragma unroll
            for (int i = 0; i < 4; ++i)
#pragma unroll
                for (int j = 0; j < 4; ++j) {
                    acc[i][j] = __builtin_amdgcn_mfma_f32_16x16x32_bf16(ah[i], bh[j], acc[i][j], 0, 0, 0);
                    acc[i][j] = __builtin_amdgcn_mfma_f32_16x16x32_bf16(ah[i], bl[j], acc[i][j], 0, 0, 0);
                    acc[i][j] = __builtin_amdgcn_mfma_f32_16x16x32_bf16(al[i], bh[j], acc[i][j], 0, 0, 0);
                }
        }
#pragma unroll
        for (int j = 0; j < 4; ++j) {
            int k = k0 + w * 64 + j * 16 + m;
            float cn = cnorm[k];
#pragma unroll
            for (int i = 0; i < 4; ++i)
#pragma unroll
                for (int r = 0; r < 4; ++r) {
                    float dv = cn - 2.f * acc[i][j][r];
                    if (dv < best[i][r]) { best[i][r] = dv; besti[i][r] = k; }
                }
        }
    }

#pragma unroll
    for (int mask = 1; mask < 16; mask <<= 1) {
#pragma unroll
        for (int i = 0; i < 4; ++i)
#pragma unroll
            for (int r = 0; r < 4; ++r) {
                float ov = __shfl_xor(best[i][r], mask);
                int oi = __shfl_xor(besti[i][r], mask);
                if (ov < best[i][r] || (ov == best[i][r] && oi < besti[i][r])) {
                    best[i][r] = ov; besti[i][r] = oi;
                }
            }
    }
    if (m == 0) {
#pragma unroll
        for (int i = 0; i < 4; ++i)
#pragma unroll
            for (int r = 0; r < 4; ++r) {
                int srow = i * 16 + q * 4 + r;
                redv[srow][w] = best[i][r];
                redi[srow][w] = besti[i][r];
            }
    }
    __syncthreads();
    if (tid < 64) {
        float bv = redv[tid][0];
        int bi = redi[tid][0];
#pragma unroll
        for (int w2 = 1; w2 < 4; ++w2) {
            float v = redv[tid][w2];
            int ii = redi[tid][w2];
            if (v < bv || (v == bv && ii < bi)) { bv = v; bi = ii; }
        }
        int n = n0 + tid;
        idx_out[n] = bi;
        idx_f_out[n] = (float)bi;
    }
}

// ---------------------------------------------------------------------------
// Fused gather + vq-sum: z_q bf16 [B][S][D] store + sum((z - cb[idx])^2).
// 8 threads per s row (16 d each).
// ---------------------------------------------------------------------------
__global__ __launch_bounds__(256) void gather_vqsum_kernel(
        const float* __restrict__ cb, const int* __restrict__ idxb,
        const short* __restrict__ z_hi, const short* __restrict__ z_lo,
        short* __restrict__ zq, float* __restrict__ acc_vq) {
    int tid = threadIdx.x;
    int b = blockIdx.y;
    int s = blockIdx.x * 32 + (tid >> 3);
    int dpart = tid & 7;
    int n = b * S_LEN + s;
    int k = idxb[n];
    const float* src = cb + (size_t)k * DCH + dpart * 16;
    size_t zoff = (size_t)n * DCH + dpart * 16;
    float sum = 0.f;
    short8 outv[2];
#pragma unroll
    for (int half = 0; half < 2; ++half) {
        float4 f0 = *(const float4*)(src + half * 8);
        float4 f1 = *(const float4*)(src + half * 8 + 4);
        bf16x8 zh = *(const bf16x8*)(z_hi + zoff + half * 8);
        bf16x8 zl = *(const bf16x8*)(z_lo + zoff + half * 8);
        float qv[8] = {f0.x, f0.y, f0.z, f0.w, f1.x, f1.y, f1.z, f1.w};
        short8 o;
#pragma unroll
        for (int e = 0; e < 8; ++e) {
            o[e] = f2bf(qv[e]);
            float zv = bf2f((unsigned short)zh[e]) + bf2f((unsigned short)zl[e]);
            float df = zv - qv[e];
            sum += df * df;
        }
        outv[half] = o;
    }
    *(short8*)(zq + zoff) = outv[0];
    *(short8*)(zq + zoff + 8) = outv[1];
    for (int off = 32; off > 0; off >>= 1) sum += __shfl_down(sum, off);
    __shared__ float wsum[4];
    if ((tid & 63) == 0) wsum[tid >> 6] = sum;
    __syncthreads();
    if (tid == 0) atomicAdd(acc_vq, wsum[0] + wsum[1] + wsum[2] + wsum[3]);
}

// ---------------------------------------------------------------------------
// Decoder bf16 MFMA conv (channels-last), unchanged.
// ---------------------------------------------------------------------------
__global__ __launch_bounds__(256) void conv_mfma_cl(
        const short* __restrict__ in, short* __restrict__ out,
        const short* __restrict__ wt, const float* __restrict__ bias,
        int Cin) {
    __shared__ short smem[24672];
    short* Xs = smem;
    short* Ws = smem + 130 * 48;

    const int tid = threadIdx.x;
    const int lane = tid & 63;
    const int w = tid >> 6;
    const int m = lane & 15;
    const int q = lane >> 4;
    const int sOff = (w & 1) * 64;
    const int cOff = (w >> 1) * 64;
    const int b = blockIdx.z;
    const int s0 = blockIdx.x * 128;
    const int co0 = blockIdx.y * 128;

    f32x4 acc[4][4];
    f32x4 zero4 = {0.f, 0.f, 0.f, 0.f};
#pragma unroll
    for (int i = 0; i < 4; ++i)
#pragma unroll
        for (int j = 0; j < 4; ++j) acc[i][j] = zero4;

    const short* inb = in + (size_t)b * S_LEN * Cin;

    for (int ci0 = 0; ci0 < Cin; ci0 += 32) {
        __syncthreads();
        for (int c = tid; c < 520; c += 256) {
            int r = c >> 2, part = c & 3;
            int s = s0 - 1 + r;
            float4 v = make_float4(0.f, 0.f, 0.f, 0.f);
            if (s >= 0 && s < S_LEN)
                v = *(const float4*)(inb + (size_t)s * Cin + ci0 + part * 8);
            *(float4*)(Xs + r * 48 + part * 8) = v;
        }
        for (int c = tid; c < 1536; c += 256) {
            int t = c >> 9;
            int rem = c & 511;
            int cr = rem >> 2, part = rem & 3;
            float4 v = *(const float4*)(wt + ((size_t)(t * 256 + co0 + cr)) * Cin + ci0 + part * 8);
            *(float4*)(Ws + (t * 128 + cr) * 48 + part * 8) = v;
        }
        __syncthreads();

#pragma unroll
        for (int t = 0; t < 3; ++t) {
            bf16x8 a[4], bb[4];
#pragma unroll
            for (int i = 0; i < 4; ++i)
                a[i] = *(const bf16x8*)(Xs + (sOff + i * 16 + m + t) * 48 + q * 8);
#pragma unroll
            for (int j = 0; j < 4; ++j)
                bb[j] = *(const bf16x8*)(Ws + (t * 128 + cOff + j * 16 + m) * 48 + q * 8);
#pragma unroll
            for (int i = 0; i < 4; ++i)
#pragma unroll
                for (int j = 0; j < 4; ++j)
                    acc[i][j] = __builtin_amdgcn_mfma_f32_16x16x32_bf16(
                        a[i], bb[j], acc[i][j], 0, 0, 0);
        }
    }

    __syncthreads();

    short* ob = smem + w * (64 * 80);
#pragma unroll
    for (int j = 0; j < 4; ++j) {
        float bv = bias[co0 + cOff + j * 16 + m];
#pragma unroll
        for (int i = 0; i < 4; ++i) {
#pragma unroll
            for (int r = 0; r < 4; ++r) {
                float val = acc[i][j][r] + bv;
                val = lrelu_f(val);
                ob[(i * 16 + q * 4 + r) * 80 + j * 16 + m] = f2bf(val);
            }
        }
    }
    const int rsel = lane >> 3;
    const int off8 = (lane & 7) * 8;
#pragma unroll
    for (int pass = 0; pass < 8; ++pass) {
        int rr = pass * 8 + rsel;
        short8 v = *(const short8*)(ob + rr * 80 + off8);
        *(short8*)(out + ((size_t)(b * S_LEN + s0 + sOff + rr)) * 256 + co0 + cOff + off8) = v;
    }
}

// ---------------------------------------------------------------------------
// Decoder conv3, LDS-tiled: h[B][S][256] bf16 -> xr[B][S] fp32, + recon sum.
// Block = 64 s; stage 66 rows x 256 ci (stride 264 shorts: +4-bank rotation
// per row -> b128 reads hit the 8-cycle minimum; unpadded 256 would be a
// same-bank pileup). 256 thr = 64 s x 4 ci-quarters.
// ---------------------------------------------------------------------------
__global__ __launch_bounds__(256) void dec_conv3_tiled_kernel(
        const short* __restrict__ h, const float* __restrict__ w3t,
        const float* __restrict__ b3, const float* __restrict__ x,
        float* __restrict__ xr, float* __restrict__ acc_recon) {
    __shared__ short Zs[66 * 264];     // 34,848 B
    __shared__ float ws[3 * 256];
    __shared__ float wsum[4];
    int tid = threadIdx.x;
    int b = blockIdx.y;
    int s0 = blockIdx.x * 64;
    const short* hb = h + (size_t)b * S_LEN * HCH;
    for (int i = tid; i < 768; i += 256) ws[i] = w3t[i];
    for (int c = tid; c < 2112; c += 256) {
        int r = c >> 5, part = c & 31;
        int g = s0 - 1 + r;
        short8 v = {0, 0, 0, 0, 0, 0, 0, 0};
        if (g >= 0 && g < S_LEN)
            v = *(const short8*)(hb + (size_t)g * HCH + part * 8);
        *(short8*)(Zs + r * 264 + part * 8) = v;
    }
    __syncthreads();

    int quarter = tid & 3;
    int sl = tid >> 2;   // 0..63
    float a0 = 0.f, a1 = 0.f, a2 = 0.f, a3 = 0.f;
#pragma unroll
    for (int t = 0; t < 3; ++t) {
        const short* zrow = Zs + (sl + t) * 264 + quarter * 64;
        const float* wrow = ws + t * 256 + quarter * 64;
#pragma unroll
        for (int c = 0; c < 8; ++c) {
            bf16x8 v = *(const bf16x8*)(zrow + c * 8);
            float4 w0 = *(const float4*)(wrow + c * 8);
            float4 w1 = *(const float4*)(wrow + c * 8 + 4);
            a0 = fmaf(w0.x, bf2f((unsigned short)v[0]), a0);
            a1 = fmaf(w0.y, bf2f((unsigned short)v[1]), a1);
            a2 = fmaf(w0.z, bf2f((unsigned short)v[2]), a2);
            a3 = fmaf(w0.w, bf2f((unsigned short)v[3]), a3);
            a0 = fmaf(w1.x, bf2f((unsigned short)v[4]), a0);
            a1 = fmaf(w1.y, bf2f((unsigned short)v[5]), a1);
            a2 = fmaf(w1.z, bf2f((unsigned short)v[6]), a2);
            a3 = fmaf(w1.w, bf2f((unsigned short)v[7]), a3);
        }
    }
    float acc = (a0 + a1) + (a2 + a3);
    acc += __shfl_xor(acc, 1);
    acc += __shfl_xor(acc, 2);
    float df2 = 0.f;
    if (quarter == 0) {
        int s = s0 + sl;
        float tot = acc + b3[0];
        xr[b * S_LEN + s] = tot;
        float df = x[b * S_LEN + s] - tot;
        df2 = df * df;
    }
    for (int off = 32; off > 0; off >>= 1) df2 += __shfl_down(df2, off);
    int lane = tid & 63, wv = tid >> 6;
    if (lane == 0) wsum[wv] = df2;
    __syncthreads();
    if (tid == 0) atomicAdd(acc_recon, wsum[0] + wsum[1] + wsum[2] + wsum[3]);
}

// ---------------------------------------------------------------------------
__global__ void finalize_kernel(const float* __restrict__ accs, float* __restrict__ out) {
    if (threadIdx.x == 0) {
        float vqm = accs[0] / ((float)BATCH * S_LEN * DCH);
        float rm  = accs[1] / ((float)BATCH * S_LEN);
        float vq_loss = vqm * 0.05f;
        float commit  = vqm * 0.15f;
        float recon   = rm * 1.0f;
        out[0] = recon + vq_loss + commit;
        out[1] = recon;
        out[2] = vq_loss;
        out[3] = commit;
    }
}

// ---------------------------------------------------------------------------
extern "C" void kernel_launch(void* const* d_in, const int* in_sizes, int n_in,
                              void* d_out, int out_size, void* d_ws, size_t ws_size,
                              hipStream_t stream) {
    const float* x    = (const float*)d_in[0];
    const float* cb   = (const float*)d_in[1];
    const float* ew1  = (const float*)d_in[2];
    const float* eb1  = (const float*)d_in[3];
    const float* ew2  = (const float*)d_in[4];
    const float* eb2  = (const float*)d_in[5];
    const float* ew3  = (const float*)d_in[6];
    const float* eb3  = (const float*)d_in[7];
    const float* dw1  = (const float*)d_in[8];
    const float* db1  = (const float*)d_in[9];
    const float* dw2  = (const float*)d_in[10];
    const float* db2  = (const float*)d_in[11];
    const float* dw3  = (const float*)d_in[12];
    const float* db3  = (const float*)d_in[13];

    float* out = (float*)d_out;
    float* xr    = out;
    float* idx_f = out + BATCH * S_LEN;
    float* loss_out = out + 2 * BATCH * S_LEN;

    const size_t NH = (size_t)BATCH * S_LEN * HCH;   // 16,777,216
    const size_t ND = (size_t)BATCH * S_LEN * DCH;   // 8,388,608

    short* sp = (short*)d_ws;
    // arena A [0, 2*NH): h1 hi/lo -> later z hi/lo -> later h1d
    short* h1_hi = sp;
    short* h1_lo = sp + NH;
    short* z_hi  = sp;            // overlays h1 (dead after conv2)
    short* z_lo  = sp + ND;
    short* h1d_bf = sp;           // overlays z (dead after vq+gather_vqsum)
    // arena B [2*NH, 4*NH): h2 hi/lo -> later zq + h2d
    short* h2_hi = sp + 2 * NH;
    short* h2_lo = sp + 3 * NH;
    short* zq_bf = sp + 2 * NH;   // overlays h2 (dead after conv3)
    short* h2d_bf = sp + 3 * NH;  // distinct from zq region
    // small buffers
    short* sm = sp + 4 * NH;
    short* cb_hi = sm; sm += KCODES * DCH;
    short* cb_lo = sm; sm += KCODES * DCH;
    short* w2_hi = sm; sm += 3 * HCH * HCH;
    short* w2_lo = sm; sm += 3 * HCH * HCH;
    short* w3_hi = sm; sm += 3 * DCH * HCH;
    short* w3_lo = sm; sm += 3 * DCH * HCH;
    short* wbf_d1 = sm; sm += 3 * 256 * DCH;
    short* wbf_d2 = sm; sm += 3 * 256 * HCH;
    float* cnorm = (float*)sm;
    int* idxb = (int*)(cnorm + KCODES);
    float* w3t = (float*)(idxb + BATCH * S_LEN);
    float* accs = w3t + 768;

    hipMemsetAsync(accs, 0, 2 * sizeof(float), stream);

    // prep
    prep_cb_split_kernel<<<2, 256, 0, stream>>>(cb, cb_hi, cb_lo, cnorm);
    prep_w_split_kernel<<<(3 * HCH * HCH + 255) / 256, 256, 0, stream>>>(ew2, w2_hi, w2_lo, HCH, HCH);
    prep_w_split_kernel<<<(3 * DCH * HCH + 255) / 256, 256, 0, stream>>>(ew3, w3_hi, w3_lo, DCH, HCH);
    prep_wdec_kernel<<<(3 * 256 * DCH + 255) / 256, 256, 0, stream>>>(dw1, wbf_d1, DCH);
    prep_wdec_kernel<<<(3 * 256 * HCH + 255) / 256, 256, 0, stream>>>(dw2, wbf_d2, HCH);
    prep_w3t_kernel<<<3, 256, 0, stream>>>(dw3, w3t);

    // encoder (split-bf16 MFMA)
    enc_conv1_cl_kernel<<<dim3(S_LEN / 32, BATCH), 256, 0, stream>>>(x, h1_hi, h1_lo, ew1, eb1);
    conv_mfma_split<<<dim3(S_LEN / 128, HCH / 128, BATCH), 256, 0, stream>>>(
        h1_hi, h1_lo, h2_hi, h2_lo, w2_hi, w2_lo, eb2, HCH, HCH, 1);
    conv_mfma_split<<<dim3(S_LEN / 128, DCH / 128, BATCH), 256, 0, stream>>>(
        h2_hi, h2_lo, z_hi, z_lo, w3_hi, w3_lo, eb3, HCH, DCH, 0);

    // VQ
    vq_mfma_kernel<<<(BATCH * S_LEN) / 64, 256, 0, stream>>>(
        z_hi, z_lo, cb_hi, cb_lo, cnorm, idxb, idx_f);
    gather_vqsum_kernel<<<dim3(S_LEN / 32, BATCH), 256, 0, stream>>>(
        cb, idxb, z_hi, z_lo, zq_bf, accs);

    // decoder (bf16 MFMA)
    conv_mfma_cl<<<dim3(S_LEN / 128, 2, BATCH), 256, 0, stream>>>(
        zq_bf, h1d_bf, wbf_d1, db1, DCH);
    conv_mfma_cl<<<dim3(S_LEN / 128, 2, BATCH), 256, 0, stream>>>(
        h1d_bf, h2d_bf, wbf_d2, db2, HCH);
    dec_conv3_tiled_kernel<<<dim3(S_LEN / 64, BATCH), 256, 0, stream>>>(
        h2d_bf, w3t, db3, x, xr, accs + 1);

    finalize_kernel<<<1, 64, 0, stream>>>(accs, loss_out);
}